// Round 7
// baseline (1017.792 us; speedup 1.0000x reference)
//
#include <hip/hip_runtime.h>
#include <stdint.h>

typedef unsigned short u16;
typedef uint8_t u8;
typedef __bf16 bf16x8 __attribute__((ext_vector_type(8)));
typedef float f32x4 __attribute__((ext_vector_type(4)));

#define NTOK 8192
#define DD 512
#define CHK 512
#define NCH 16
#define KSPLIT 4
#define KLEN 2048
#define LOG2E 1.4426950408889634f
#define SCL 0.044194173824159216f          // 1/sqrt(512)
#define SCLL 0.063762069130835270f         // SCL * LOG2E

__device__ __forceinline__ u16 f2bf(float f) {
  union { float f; uint32_t u; } v; v.f = f;
  uint32_t r = v.u + 0x7FFFu + ((v.u >> 16) & 1u);
  return (u16)(r >> 16);
}

// DPP-based 16-lane (row) sum: stays on VALU pipe, avoids LDS-pipe shuffles.
template <int CTRL>
__device__ __forceinline__ float dppadd(float x) {
  int y = __builtin_amdgcn_update_dpp(0, __float_as_int(x), CTRL, 0xF, 0xF, true);
  return x + __int_as_float(y);
}
__device__ __forceinline__ float rowsum16(float x) {
  x = dppadd<0xB1>(x);    // quad_perm(1,0,3,2)
  x = dppadd<0x4E>(x);    // quad_perm(2,3,0,1)
  x = dppadd<0x141>(x);   // row_half_mirror
  x = dppadd<0x140>(x);   // row_mirror
  return x;
}

// async global->LDS, 16B per lane. LDS dest is wave-uniform base + lane*16.
typedef const __attribute__((address_space(1))) unsigned int* gas_t;
typedef __attribute__((address_space(3))) unsigned int* las_t;
__device__ __forceinline__ void gload16(const void* g, void* l) {
  __builtin_amdgcn_global_load_lds((gas_t)g, (las_t)l, 16, 0, 0);
}

// token permutation within 64-groups (applied to both P cols and vT rows; PV
// contracts over the same permuted coordinate so results are unchanged)
__device__ __forceinline__ int permtok(int t) {
  return (t & ~63) | (((t & 15) << 2) | ((t >> 4) & 3));
}

// ---------------- prep: cast x->bf16 (+zero lsum), transpose 4 weights, cls q0 ----------------
__global__ void prep_kernel(const float* __restrict__ x, const float* __restrict__ Wq,
                            const float* __restrict__ Wk, const float* __restrict__ Wv,
                            const float* __restrict__ Wo, const float* __restrict__ bq,
                            u16* __restrict__ xb, u16* __restrict__ Wall, u16* __restrict__ WoT,
                            float* __restrict__ lsum, float* __restrict__ q0g) {
  __shared__ float t[32][33];
  const int bid = blockIdx.x;
  const int tid = threadIdx.x;
  if (bid < 4096) {
    int i = bid * 256 + tid;
    if (bid < 32) lsum[bid * 256 + tid] = 0.f;
    float4 v = ((const float4*)x)[i];
    ushort4 o;
    o.x = f2bf(v.x); o.y = f2bf(v.y); o.z = f2bf(v.z); o.w = f2bf(v.w);
    ((ushort4*)xb)[i] = o;
  } else if (bid < 5120) {
    const int tt = bid - 4096;
    const int z = tt >> 8, idx = tt & 255;
    const float* W; u16* WT;
    if (z == 0)      { W = Wq; WT = Wall; }
    else if (z == 1) { W = Wk; WT = Wall + 512 * 512; }
    else if (z == 2) { W = Wv; WT = Wall + 2 * 512 * 512; }
    else             { W = Wo; WT = WoT; }
    const int n0 = (idx & 15) * 32, k0 = (idx >> 4) * 32;
    const int tx = tid & 31, ty = tid >> 5;  // 32 x 8
    #pragma unroll
    for (int i = 0; i < 4; i++)
      t[ty + 8 * i][tx] = W[(k0 + ty + 8 * i) * DD + n0 + tx];
    __syncthreads();
    #pragma unroll
    for (int i = 0; i < 4; i++)
      WT[(n0 + ty + 8 * i) * DD + k0 + tx] = f2bf(t[tx][ty + 8 * i]);
  } else {
    const int c = (bid - 5120) * 256 + tid;
    float acc = bq[c];
    #pragma unroll 8
    for (int i = 0; i < 512; i++) acc += x[i] * Wq[i * 512 + c];
    q0g[c] = acc;
  }
}

// ---------------- fused q/k/v projection: 256 thr, 128x128 tiles ----------------
// by: 0..11; which = by>>2 (0=q scaled by SCLL, 1=k, 2=v transposed+permuted fp8 out)
__launch_bounds__(256, 3)
__global__ void qkv_kernel(const u16* __restrict__ A, const u16* __restrict__ Wall,
                           const float* __restrict__ bq, const float* __restrict__ bk,
                           const float* __restrict__ bv, u16* __restrict__ qb,
                           u16* __restrict__ kb, u8* __restrict__ vT8) {
  __shared__ __align__(16) u16 As[128 * 32];
  __shared__ __align__(16) u16 Bs[128 * 32];
  const int m0 = blockIdx.x * 128;
  const int n0g = blockIdx.y * 128;
  const int which = blockIdx.y >> 2;
  const int n0 = n0g & 511;
  const int tid = threadIdx.x;
  const int w = tid >> 6, lane = tid & 63, lm = lane & 15, quad = lane >> 4;
  const int wm = w & 1, wn = w >> 1;
  f32x4 acc[4][4] = {};
  const int soff = tid * 16;
  const int srow = soff >> 6;
  const int scol = soff & 63;
  const char* Ag = (const char*)A + ((size_t)(m0 + srow) * DD) * 2 + scol;
  const char* Bg = (const char*)Wall + ((size_t)(n0g + srow) * DD) * 2 + scol;
  char* Al = (char*)As + w * 1024;
  char* Bl = (char*)Bs + w * 1024;
  const size_t rs = (size_t)64 * DD * 2;
  for (int kk = 0; kk < DD; kk += 32) {
    const char* ag = Ag + (size_t)kk * 2;
    const char* bg = Bg + (size_t)kk * 2;
    gload16(ag, Al);
    gload16(ag + rs, Al + 4096);
    gload16(bg, Bl);
    gload16(bg + rs, Bl + 4096);
    __syncthreads();
    bf16x8 af[4], bfr[4];
    #pragma unroll
    for (int i = 0; i < 4; i++) af[i] = *(const bf16x8*)&As[(wm * 64 + i * 16 + lm) * 32 + quad * 8];
    #pragma unroll
    for (int j = 0; j < 4; j++) bfr[j] = *(const bf16x8*)&Bs[(wn * 64 + j * 16 + lm) * 32 + quad * 8];
    #pragma unroll
    for (int i = 0; i < 4; i++)
      #pragma unroll
      for (int j = 0; j < 4; j++)
        acc[i][j] = __builtin_amdgcn_mfma_f32_16x16x32_bf16(af[i], bfr[j], acc[i][j], 0, 0, 0);
    __syncthreads();
  }
  const float* bias = (which == 0) ? bq : (which == 1) ? bk : bv;
  #pragma unroll
  for (int i = 0; i < 4; i++) {
    const int row0 = m0 + wm * 64 + i * 16 + quad * 4;
    #pragma unroll
    for (int j = 0; j < 4; j++) {
      const int col = n0 + wn * 64 + j * 16 + lm;
      const float bv_ = bias[col];
      if (which == 0) {
        #pragma unroll
        for (int r = 0; r < 4; r++)
          qb[(size_t)(row0 + r) * DD + col] = f2bf((acc[i][j][r] + bv_) * SCLL);
      } else if (which == 1) {
        #pragma unroll
        for (int r = 0; r < 4; r++)
          kb[(size_t)(row0 + r) * DD + col] = f2bf(acc[i][j][r] + bv_);
      } else {
        #pragma unroll
        for (int r = 0; r < 4; r++) {
          const float val = acc[i][j][r] + bv_;
          uint32_t pk = __builtin_amdgcn_cvt_pk_fp8_f32(val, val, 0, false);
          vT8[(size_t)col * NTOK + permtok(row0 + r)] = (u8)(pk & 0xFF);
        }
      }
    }
  }
}

// ---------------- out projection: 256 thr, 128x128 tiles, bf16 in / fp32+resid out ----------------
__launch_bounds__(256, 3)
__global__ void outproj_kernel(const u16* __restrict__ A, const u16* __restrict__ BT,
                               const float* __restrict__ bias, float* __restrict__ outp,
                               const float* __restrict__ resid) {
  __shared__ __align__(16) u16 As[128 * 32];
  __shared__ __align__(16) u16 Bs[128 * 32];
  const int m0 = blockIdx.x * 128, n0 = blockIdx.y * 128;
  const int tid = threadIdx.x;
  const int w = tid >> 6, lane = tid & 63, lm = lane & 15, quad = lane >> 4;
  const int wm = w & 1, wn = w >> 1;
  f32x4 acc[4][4] = {};
  const int soff = tid * 16;
  const int srow = soff >> 6;
  const int scol = soff & 63;
  const char* Ag = (const char*)A + ((size_t)(m0 + srow) * DD) * 2 + scol;
  const char* Bg = (const char*)BT + ((size_t)(n0 + srow) * DD) * 2 + scol;
  char* Al = (char*)As + w * 1024;
  char* Bl = (char*)Bs + w * 1024;
  const size_t rs = (size_t)64 * DD * 2;
  for (int kk = 0; kk < DD; kk += 32) {
    const char* ag = Ag + (size_t)kk * 2;
    const char* bg = Bg + (size_t)kk * 2;
    gload16(ag, Al);
    gload16(ag + rs, Al + 4096);
    gload16(bg, Bl);
    gload16(bg + rs, Bl + 4096);
    __syncthreads();
    bf16x8 af[4], bfr[4];
    #pragma unroll
    for (int i = 0; i < 4; i++) af[i] = *(const bf16x8*)&As[(wm * 64 + i * 16 + lm) * 32 + quad * 8];
    #pragma unroll
    for (int j = 0; j < 4; j++) bfr[j] = *(const bf16x8*)&Bs[(wn * 64 + j * 16 + lm) * 32 + quad * 8];
    #pragma unroll
    for (int i = 0; i < 4; i++)
      #pragma unroll
      for (int j = 0; j < 4; j++)
        acc[i][j] = __builtin_amdgcn_mfma_f32_16x16x32_bf16(af[i], bfr[j], acc[i][j], 0, 0, 0);
    __syncthreads();
  }
  #pragma unroll
  for (int i = 0; i < 4; i++) {
    const int row0 = m0 + wm * 64 + i * 16 + quad * 4;
    #pragma unroll
    for (int j = 0; j < 4; j++) {
      const int col = n0 + wn * 64 + j * 16 + lm;
      const float bv = bias[col];
      #pragma unroll
      for (int r = 0; r < 4; r++) {
        const size_t idx = (size_t)(row0 + r) * DD + col;
        outp[idx] = acc[i][j][r] + bv + resid[idx];
      }
    }
  }
}

// ---------------- fp8 PV GEMM: 256 thr, 128x128 tiles, BK=64 ----------------
// MODE 3: bf16 out scaled by 1/lsum[row]; MODE 4: fp32 partial, K-range by blockIdx.z
template <int MODE>
__launch_bounds__(256, 3)
__global__ void gemm_fp8_kernel(const u8* __restrict__ A, const u8* __restrict__ BT,
                                int K, int lda, int ldb, void* __restrict__ outp,
                                const float* __restrict__ lsum) {
  __shared__ __align__(16) u8 As[128 * 64];
  __shared__ __align__(16) u8 Bs[128 * 64];
  const int m0 = blockIdx.x * 128, n0 = blockIdx.y * 128;
  const int tid = threadIdx.x;
  const int w = tid >> 6, lane = tid & 63, lm = lane & 15, quad = lane >> 4;
  const int wm = w & 1, wn = w >> 1;
  f32x4 acc[4][4] = {};
  const int soff = tid * 16;
  const int srow = soff >> 6;   // 0..63
  const int scol = soff & 63;
  const size_t kbase = (MODE == 4) ? (size_t)blockIdx.z * (size_t)K : 0;
  const u8* Ag = A + (size_t)(m0 + srow) * lda + kbase + scol;
  const u8* Bg = BT + (size_t)(n0 + srow) * ldb + kbase + scol;
  u8* Al = As + w * 1024;
  u8* Bl = Bs + w * 1024;
  const size_t ars = (size_t)64 * lda;
  const size_t brs = (size_t)64 * ldb;
  for (int kk = 0; kk < K; kk += 64) {
    const u8* ag = Ag + kk;
    const u8* bg = Bg + kk;
    gload16(ag, Al);
    gload16(ag + ars, Al + 4096);
    gload16(bg, Bl);
    gload16(bg + brs, Bl + 4096);
    __syncthreads();
    #pragma unroll
    for (int kk2 = 0; kk2 < 64; kk2 += 32) {
      long af[4], bfr[4];
      #pragma unroll
      for (int i = 0; i < 4; i++)
        af[i] = *(const long*)&As[(wm * 64 + i * 16 + lm) * 64 + kk2 + quad * 8];
      #pragma unroll
      for (int j = 0; j < 4; j++)
        bfr[j] = *(const long*)&Bs[(wn * 64 + j * 16 + lm) * 64 + kk2 + quad * 8];
      #pragma unroll
      for (int i = 0; i < 4; i++)
        #pragma unroll
        for (int j = 0; j < 4; j++)
          acc[i][j] = __builtin_amdgcn_mfma_f32_16x16x32_fp8_fp8(af[i], bfr[j], acc[i][j], 0, 0, 0);
    }
    __syncthreads();
  }
  #pragma unroll
  for (int i = 0; i < 4; i++) {
    const int row0 = m0 + wm * 64 + i * 16 + quad * 4;
    float li[4];
    if (MODE == 3) {
      #pragma unroll
      for (int r = 0; r < 4; r++) li[r] = 1.0f / lsum[row0 + r];
    }
    #pragma unroll
    for (int j = 0; j < 4; j++) {
      const int col = n0 + wn * 64 + j * 16 + lm;
      if (MODE == 3) {
        #pragma unroll
        for (int r = 0; r < 4; r++)
          ((u16*)outp)[(size_t)(row0 + r) * DD + col] = f2bf(acc[i][j][r] * li[r]);
      } else {
        float* po = (float*)outp + (size_t)blockIdx.z * NTOK * DD;
        #pragma unroll
        for (int r = 0; r < 4; r++)
          po[(size_t)(row0 + r) * DD + col] = acc[i][j][r];
      }
    }
  }
}

// ---------------- split-K PV reduce (4 parts): attnb = (sum parts) / lsum ----------------
__global__ void pv_reduce_kernel(const float* __restrict__ part, const float* __restrict__ lsum,
                                 u16* __restrict__ attnb) {
  const int idx = blockIdx.x * 256 + threadIdx.x;
  const int row = idx >> 7;
  const int c4 = (idx & 127) << 2;
  const float* p = part + (size_t)row * DD + c4;
  const size_t stride = (size_t)NTOK * DD;
  float4 a = *(const float4*)(p);
  float4 b = *(const float4*)(p + stride);
  float4 c = *(const float4*)(p + 2 * stride);
  float4 d = *(const float4*)(p + 3 * stride);
  const float inv = 1.0f / lsum[row];
  ushort4 o;
  o.x = f2bf((a.x + b.x + c.x + d.x) * inv);
  o.y = f2bf((a.y + b.y + c.y + d.y) * inv);
  o.z = f2bf((a.z + b.z + c.z + d.z) * inv);
  o.w = f2bf((a.w + b.w + c.w + d.w) * inv);
  *(ushort4*)(attnb + (size_t)row * DD + c4) = o;
}

// ---------------- scores: 128 q-rows x 512-key chunk per block, 1024 thr ----------------
// q pre-scaled by SCL*LOG2E; max-free chunk softmax; P stored fp8 permuted-packed (dword)
__launch_bounds__(1024, 8)
__global__ void scores_kernel(const u16* __restrict__ qb, const u16* __restrict__ kb,
                              u8* __restrict__ P8, float* __restrict__ lsum) {
  __shared__ __align__(16) u16 As[128 * 32];   // 8 KB
  __shared__ __align__(16) u16 Bs[512 * 32];   // 32 KB
  __shared__ float hS[8][128], hP[8][128], hZ[128];
  const int m0 = blockIdx.x * 128;
  const int c = blockIdx.y;
  const int tid = threadIdx.x;
  const int w = tid >> 6, lane = tid & 63, lm = lane & 15, quad = lane >> 4;
  const int mt = w & 1, wsl = w >> 1;
  f32x4 s[4][4] = {};
  const int srA = tid >> 2, scA = (tid & 3) * 16;
  const char* Qg = (const char*)qb + ((size_t)(m0 + srA) * DD) * 2 + scA;
  const char* Kg = (const char*)kb + ((size_t)(c * CHK + srA) * DD) * 2 + scA;
  char* Al = (char*)As + w * 1024;
  char* Bl = (char*)Bs + w * 1024;
  for (int kk = 0; kk < DD; kk += 32) {
    if (tid < 512) gload16(Qg + kk * 2, Al);
    gload16(Kg + kk * 2, Bl);
    gload16(Kg + kk * 2 + (size_t)256 * DD * 2, Bl + 16384);
    __syncthreads();
    bf16x8 af[4], bfr[4];
    #pragma unroll
    for (int i = 0; i < 4; i++) af[i] = *(const bf16x8*)&As[(mt * 64 + i * 16 + lm) * 32 + quad * 8];
    #pragma unroll
    for (int j = 0; j < 4; j++) bfr[j] = *(const bf16x8*)&Bs[(wsl * 64 + j * 16 + lm) * 32 + quad * 8];
    #pragma unroll
    for (int i = 0; i < 4; i++)
      #pragma unroll
      for (int j = 0; j < 4; j++)
        s[i][j] = __builtin_amdgcn_mfma_f32_16x16x32_bf16(af[i], bfr[j], s[i][j], 0, 0, 0);
    __syncthreads();
  }
  // ---- phase A: e = exp2(s*log2e); per-wave (64-col) partial row sums (DPP) ----
  #pragma unroll
  for (int i = 0; i < 4; i++) {
    #pragma unroll
    for (int reg = 0; reg < 4; reg++) {
      float z = 0.f;
      #pragma unroll
      for (int j = 0; j < 4; j++) {
        float e = exp2f(s[i][j][reg]);
        s[i][j][reg] = e;
        z += e;
      }
      z = rowsum16(z);
      if (lm == 0) hS[wsl][mt * 64 + i * 16 + quad * 4 + reg] = z;
    }
  }
  __syncthreads();
  // ---- phase B: row totals -> hZ = LOG2E / Z ----
  if (tid < 128) {
    float t = 0.f;
    #pragma unroll
    for (int w2 = 0; w2 < 8; w2++) t += hS[w2][tid];
    hZ[tid] = LOG2E / t;
  }
  __syncthreads();
  // ---- phase C: p = exp2(e * LOG2E/Z); fp8 packed permuted store; partial l ----
  #pragma unroll
  for (int i = 0; i < 4; i++) {
    #pragma unroll
    for (int reg = 0; reg < 4; reg++) {
      const int rl = mt * 64 + i * 16 + quad * 4 + reg;
      const float iz = hZ[rl];
      const float p0 = exp2f(s[i][0][reg] * iz);
      const float p1 = exp2f(s[i][1][reg] * iz);
      const float p2 = exp2f(s[i][2][reg] * iz);
      const float p3 = exp2f(s[i][3][reg] * iz);
      float zp = (p0 + p1) + (p2 + p3);
      zp = rowsum16(zp);
      if (lm == 0) hP[wsl][rl] = zp;
      uint32_t o = __builtin_amdgcn_cvt_pk_fp8_f32(p0, p1, 0, false);
      o = __builtin_amdgcn_cvt_pk_fp8_f32(p2, p3, o, true);
      *(uint32_t*)(P8 + (size_t)(m0 + rl) * NTOK + c * CHK + wsl * 64 + lm * 4) = o;
    }
  }
  __syncthreads();
  if (tid < 128) {
    float t = 0.f;
    #pragma unroll
    for (int w2 = 0; w2 < 8; w2++) t += hP[w2][tid];
    atomicAdd(&lsum[m0 + tid], t);
  }
}

// ---------------- cls row (exact fp32) ----------------
__global__ void cls_u_kernel(const float* __restrict__ Wk, const float* __restrict__ bk,
                             const float* __restrict__ q0g, float* __restrict__ uc) {
  __shared__ float q0[512];
  const int tid = threadIdx.x;
  q0[tid] = q0g[tid];
  q0[tid + 256] = q0g[tid + 256];
  __syncthreads();
  if (blockIdx.x < 8) {
    const int c = blockIdx.x * 64 + (tid >> 2), ii = tid & 3;
    float acc = 0.f;
    #pragma unroll 8
    for (int j = ii; j < 512; j += 4) acc += Wk[(size_t)c * 512 + j] * q0[j];
    acc += __shfl_xor(acc, 1, 64);
    acc += __shfl_xor(acc, 2, 64);
    if (ii == 0) uc[c] = acc;
  } else if (tid < 64) {
    float acc = 0.f;
    #pragma unroll 8
    for (int j = tid; j < 512; j += 64) acc += bk[j] * q0[j];
    #pragma unroll
    for (int off = 1; off < 64; off <<= 1) acc += __shfl_xor(acc, off, 64);
    if (tid == 0) uc[512] = acc;
  }
}

__global__ void cls_scores_kernel(const float* __restrict__ x, const float* __restrict__ uc,
                                  float* __restrict__ s0) {
  __shared__ float u[512];
  __shared__ float c0s;
  int tid = threadIdx.x;  // 256
  for (int i = tid; i < 512; i += 256) u[i] = uc[i];
  if (tid == 0) c0s = uc[512];
  __syncthreads();
  int rowg = blockIdx.x * 32 + (tid >> 3);
  int ii = tid & 7;
  const float* xr = x + rowg * 512;
  float acc = 0.f;
  for (int i = ii; i < 512; i += 8) acc += xr[i] * u[i];
  acc += __shfl_xor(acc, 1, 64);
  acc += __shfl_xor(acc, 2, 64);
  acc += __shfl_xor(acc, 4, 64);
  if (ii == 0) s0[rowg] = (acc + c0s) * SCL;
}

__global__ void cls_softmax_kernel(const float* __restrict__ s0, float* __restrict__ out) {
  int tid = threadIdx.x;  // 1024 = 16 waves, wave w = chunk w
  int w = tid >> 6, lane = tid & 63;
  const float* sc = s0 + w * 512;
  float v[8];
  float m = -1e30f;
  #pragma unroll
  for (int j = 0; j < 8; j++) { v[j] = sc[lane * 8 + j]; m = fmaxf(m, v[j]); }
  for (int off = 1; off < 64; off <<= 1) m = fmaxf(m, __shfl_xor(m, off, 64));
  float z = 0.f;
  #pragma unroll
  for (int j = 0; j < 8; j++) { v[j] = expf(v[j] - m); z += v[j]; }
  for (int off = 1; off < 64; off <<= 1) z += __shfl_xor(z, off, 64);
  float invz = 1.f / z;
  float l = 0.f;
  #pragma unroll
  for (int j = 0; j < 8; j++) { v[j] = expf(v[j] * invz); l += v[j]; }
  for (int off = 1; off < 64; off <<= 1) l += __shfl_xor(l, off, 64);
  __shared__ float lw[16];
  if (lane == 0) lw[w] = l;
  __syncthreads();
  float L = 0.f;
  for (int i = 0; i < 16; i++) L += lw[i];
  float invL = 1.f / L;
  #pragma unroll
  for (int j = 0; j < 8; j++) out[w * 512 + lane * 8 + j] = v[j] * invL;
}

extern "C" void kernel_launch(void* const* d_in, const int* in_sizes, int n_in,
                              void* d_out, int out_size, void* d_ws, size_t ws_size,
                              hipStream_t stream) {
  const float* x  = (const float*)d_in[0];
  const float* Wq = (const float*)d_in[1];
  const float* bq = (const float*)d_in[2];
  const float* Wk = (const float*)d_in[3];
  const float* bk = (const float*)d_in[4];
  const float* Wv = (const float*)d_in[5];
  const float* bv = (const float*)d_in[6];
  const float* Wo = (const float*)d_in[7];
  const float* bo = (const float*)d_in[8];
  float* out = (float*)d_out;

  char* ws = (char*)d_ws;
  u16* xb    = (u16*)(ws);                  // 8 MB
  u16* Wall  = (u16*)(ws + 8388608);        // 1.5 MB
  u16* WoT   = (u16*)(ws + 9961472);        // 512 KB
  u16* qb    = (u16*)(ws + 10485760);       // 8 MB (pre-scaled by SCL*LOG2E)
  u16* kb    = (u16*)(ws + 18874368);       // 8 MB
  u8*  vT8   = (u8*)(ws + 27262976);        // 4 MB fp8 (token-permuted)
  u16* attnb = (u16*)(ws + 35651584);       // 8 MB
  float* q0g = (float*)(ws + 44040192);     // 512 f
  float* uc  = (float*)(ws + 44042240);     // 513 f
  float* s0  = (float*)(ws + 44048384);     // 8192 f
  float* lsum= (float*)(ws + 44081152);     // 8192 f
  u8*  P8    = (u8*)(ws + 44113920);        // 64 MB fp8 (token-permuted cols)
  float* part= (float*)(ws + 111222784);    // 4 x 16 MB
  const size_t need_P    = 111222784ULL;
  const size_t need_full = 111222784ULL + (size_t)KSPLIT * NTOK * DD * 4ULL;  // 178 MB, known-good

  prep_kernel<<<5122, 256, 0, stream>>>(x, Wq, Wk, Wv, Wo, bq, xb, Wall, WoT, lsum, q0g);

  qkv_kernel<<<dim3(NTOK / 128, 12), 256, 0, stream>>>(xb, Wall, bq, bk, bv, qb, kb, vT8);

  scores_kernel<<<dim3(NTOK / 128, NCH), 1024, 0, stream>>>(qb, kb, P8, lsum);

  if (ws_size >= need_full) {
    gemm_fp8_kernel<4><<<dim3(NTOK / 128, DD / 128, KSPLIT), 256, 0, stream>>>(
        P8, vT8, KLEN, NTOK, NTOK, part, nullptr);
    pv_reduce_kernel<<<NTOK * DD / 4 / 256, 256, 0, stream>>>(part, lsum, attnb);
  } else {
    gemm_fp8_kernel<3><<<dim3(NTOK / 128, DD / 128), 256, 0, stream>>>(
        P8, vT8, NTOK, NTOK, NTOK, attnb, lsum);
  }

  outproj_kernel<<<dim3(NTOK / 128, DD / 128), 256, 0, stream>>>(attnb, WoT, bo, out, x);

  cls_u_kernel<<<9, 256, 0, stream>>>(Wk, bk, q0g, uc);
  cls_scores_kernel<<<NTOK / 32, 256, 0, stream>>>(x, uc, s0);
  cls_softmax_kernel<<<1, 1024, 0, stream>>>(s0, out + (size_t)NTOK * DD);
}

// Round 8
// 347.229 us; speedup vs baseline: 2.9312x; 2.9312x over previous
//
#include <hip/hip_runtime.h>
#include <stdint.h>

typedef unsigned short u16;
typedef uint8_t u8;
typedef __bf16 bf16x8 __attribute__((ext_vector_type(8)));
typedef float f32x4 __attribute__((ext_vector_type(4)));

#define NTOK 8192
#define DD 512
#define CHK 512
#define NCH 16
#define KSPLIT 4
#define KLEN 2048
#define LOG2E 1.4426950408889634f
#define SCL 0.044194173824159216f          // 1/sqrt(512)
#define SCLL 0.063762069130835270f         // SCL * LOG2E

__device__ __forceinline__ u16 f2bf(float f) {
  union { float f; uint32_t u; } v; v.f = f;
  uint32_t r = v.u + 0x7FFFu + ((v.u >> 16) & 1u);
  return (u16)(r >> 16);
}

// DPP-based 16-lane (row) sum: stays on VALU pipe, avoids LDS-pipe shuffles.
template <int CTRL>
__device__ __forceinline__ float dppadd(float x) {
  int y = __builtin_amdgcn_update_dpp(0, __float_as_int(x), CTRL, 0xF, 0xF, true);
  return x + __int_as_float(y);
}
__device__ __forceinline__ float rowsum16(float x) {
  x = dppadd<0xB1>(x);    // quad_perm(1,0,3,2)
  x = dppadd<0x4E>(x);    // quad_perm(2,3,0,1)
  x = dppadd<0x141>(x);   // row_half_mirror
  x = dppadd<0x140>(x);   // row_mirror
  return x;
}

// async global->LDS, 16B per lane. LDS dest is wave-uniform base + lane*16.
typedef const __attribute__((address_space(1))) unsigned int* gas_t;
typedef __attribute__((address_space(3))) unsigned int* las_t;
__device__ __forceinline__ void gload16(const void* g, void* l) {
  __builtin_amdgcn_global_load_lds((gas_t)g, (las_t)l, 16, 0, 0);
}

// token permutation within 64-groups (applied to both P cols and vT rows; PV
// contracts over the same permuted coordinate so results are unchanged)
__device__ __forceinline__ int permtok(int t) {
  return (t & ~63) | (((t & 15) << 2) | ((t >> 4) & 3));
}

// ---------------- prep: cast x->bf16 (+zero lsum), transpose 4 weights, cls q0 ----------------
__global__ void prep_kernel(const float* __restrict__ x, const float* __restrict__ Wq,
                            const float* __restrict__ Wk, const float* __restrict__ Wv,
                            const float* __restrict__ Wo, const float* __restrict__ bq,
                            u16* __restrict__ xb, u16* __restrict__ Wall, u16* __restrict__ WoT,
                            float* __restrict__ lsum, float* __restrict__ q0g) {
  __shared__ float t[32][33];
  const int bid = blockIdx.x;
  const int tid = threadIdx.x;
  if (bid < 4096) {
    int i = bid * 256 + tid;
    if (bid < 32) lsum[bid * 256 + tid] = 0.f;
    float4 v = ((const float4*)x)[i];
    ushort4 o;
    o.x = f2bf(v.x); o.y = f2bf(v.y); o.z = f2bf(v.z); o.w = f2bf(v.w);
    ((ushort4*)xb)[i] = o;
  } else if (bid < 5120) {
    const int tt = bid - 4096;
    const int z = tt >> 8, idx = tt & 255;
    const float* W; u16* WT;
    if (z == 0)      { W = Wq; WT = Wall; }
    else if (z == 1) { W = Wk; WT = Wall + 512 * 512; }
    else if (z == 2) { W = Wv; WT = Wall + 2 * 512 * 512; }
    else             { W = Wo; WT = WoT; }
    const int n0 = (idx & 15) * 32, k0 = (idx >> 4) * 32;
    const int tx = tid & 31, ty = tid >> 5;  // 32 x 8
    #pragma unroll
    for (int i = 0; i < 4; i++)
      t[ty + 8 * i][tx] = W[(k0 + ty + 8 * i) * DD + n0 + tx];
    __syncthreads();
    #pragma unroll
    for (int i = 0; i < 4; i++)
      WT[(n0 + ty + 8 * i) * DD + k0 + tx] = f2bf(t[tx][ty + 8 * i]);
  } else {
    const int c = (bid - 5120) * 256 + tid;
    float acc = bq[c];
    #pragma unroll 8
    for (int i = 0; i < 512; i++) acc += x[i] * Wq[i * 512 + c];
    q0g[c] = acc;
  }
}

// ---------------- fused q/k/v projection: 256 thr, 128x128 tiles ----------------
// by: 0..11; which = by>>2 (0=q scaled by SCLL, 1=k, 2=v transposed+permuted fp8 out)
__launch_bounds__(256, 3)
__global__ void qkv_kernel(const u16* __restrict__ A, const u16* __restrict__ Wall,
                           const float* __restrict__ bq, const float* __restrict__ bk,
                           const float* __restrict__ bv, u16* __restrict__ qb,
                           u16* __restrict__ kb, u8* __restrict__ vT8) {
  __shared__ __align__(16) u16 As[128 * 32];
  __shared__ __align__(16) u16 Bs[128 * 32];
  const int m0 = blockIdx.x * 128;
  const int n0g = blockIdx.y * 128;
  const int which = blockIdx.y >> 2;
  const int n0 = n0g & 511;
  const int tid = threadIdx.x;
  const int w = tid >> 6, lane = tid & 63, lm = lane & 15, quad = lane >> 4;
  const int wm = w & 1, wn = w >> 1;
  f32x4 acc[4][4] = {};
  const int soff = tid * 16;
  const int srow = soff >> 6;
  const int scol = soff & 63;
  const char* Ag = (const char*)A + ((size_t)(m0 + srow) * DD) * 2 + scol;
  const char* Bg = (const char*)Wall + ((size_t)(n0g + srow) * DD) * 2 + scol;
  char* Al = (char*)As + w * 1024;
  char* Bl = (char*)Bs + w * 1024;
  const size_t rs = (size_t)64 * DD * 2;
  for (int kk = 0; kk < DD; kk += 32) {
    const char* ag = Ag + (size_t)kk * 2;
    const char* bg = Bg + (size_t)kk * 2;
    gload16(ag, Al);
    gload16(ag + rs, Al + 4096);
    gload16(bg, Bl);
    gload16(bg + rs, Bl + 4096);
    __syncthreads();
    bf16x8 af[4], bfr[4];
    #pragma unroll
    for (int i = 0; i < 4; i++) af[i] = *(const bf16x8*)&As[(wm * 64 + i * 16 + lm) * 32 + quad * 8];
    #pragma unroll
    for (int j = 0; j < 4; j++) bfr[j] = *(const bf16x8*)&Bs[(wn * 64 + j * 16 + lm) * 32 + quad * 8];
    #pragma unroll
    for (int i = 0; i < 4; i++)
      #pragma unroll
      for (int j = 0; j < 4; j++)
        acc[i][j] = __builtin_amdgcn_mfma_f32_16x16x32_bf16(af[i], bfr[j], acc[i][j], 0, 0, 0);
    __syncthreads();
  }
  const float* bias = (which == 0) ? bq : (which == 1) ? bk : bv;
  #pragma unroll
  for (int i = 0; i < 4; i++) {
    const int row0 = m0 + wm * 64 + i * 16 + quad * 4;
    #pragma unroll
    for (int j = 0; j < 4; j++) {
      const int col = n0 + wn * 64 + j * 16 + lm;
      const float bv_ = bias[col];
      if (which == 0) {
        #pragma unroll
        for (int r = 0; r < 4; r++)
          qb[(size_t)(row0 + r) * DD + col] = f2bf((acc[i][j][r] + bv_) * SCLL);
      } else if (which == 1) {
        #pragma unroll
        for (int r = 0; r < 4; r++)
          kb[(size_t)(row0 + r) * DD + col] = f2bf(acc[i][j][r] + bv_);
      } else {
        #pragma unroll
        for (int r = 0; r < 4; r++) {
          const float val = acc[i][j][r] + bv_;
          uint32_t pk = __builtin_amdgcn_cvt_pk_fp8_f32(val, val, 0, false);
          vT8[(size_t)col * NTOK + permtok(row0 + r)] = (u8)(pk & 0xFF);
        }
      }
    }
  }
}

// ---------------- out projection: 256 thr, 128x128 tiles, bf16 in / fp32+resid out ----------------
__launch_bounds__(256, 3)
__global__ void outproj_kernel(const u16* __restrict__ A, const u16* __restrict__ BT,
                               const float* __restrict__ bias, float* __restrict__ outp,
                               const float* __restrict__ resid) {
  __shared__ __align__(16) u16 As[128 * 32];
  __shared__ __align__(16) u16 Bs[128 * 32];
  const int m0 = blockIdx.x * 128, n0 = blockIdx.y * 128;
  const int tid = threadIdx.x;
  const int w = tid >> 6, lane = tid & 63, lm = lane & 15, quad = lane >> 4;
  const int wm = w & 1, wn = w >> 1;
  f32x4 acc[4][4] = {};
  const int soff = tid * 16;
  const int srow = soff >> 6;
  const int scol = soff & 63;
  const char* Ag = (const char*)A + ((size_t)(m0 + srow) * DD) * 2 + scol;
  const char* Bg = (const char*)BT + ((size_t)(n0 + srow) * DD) * 2 + scol;
  char* Al = (char*)As + w * 1024;
  char* Bl = (char*)Bs + w * 1024;
  const size_t rs = (size_t)64 * DD * 2;
  for (int kk = 0; kk < DD; kk += 32) {
    const char* ag = Ag + (size_t)kk * 2;
    const char* bg = Bg + (size_t)kk * 2;
    gload16(ag, Al);
    gload16(ag + rs, Al + 4096);
    gload16(bg, Bl);
    gload16(bg + rs, Bl + 4096);
    __syncthreads();
    bf16x8 af[4], bfr[4];
    #pragma unroll
    for (int i = 0; i < 4; i++) af[i] = *(const bf16x8*)&As[(wm * 64 + i * 16 + lm) * 32 + quad * 8];
    #pragma unroll
    for (int j = 0; j < 4; j++) bfr[j] = *(const bf16x8*)&Bs[(wn * 64 + j * 16 + lm) * 32 + quad * 8];
    #pragma unroll
    for (int i = 0; i < 4; i++)
      #pragma unroll
      for (int j = 0; j < 4; j++)
        acc[i][j] = __builtin_amdgcn_mfma_f32_16x16x32_bf16(af[i], bfr[j], acc[i][j], 0, 0, 0);
    __syncthreads();
  }
  #pragma unroll
  for (int i = 0; i < 4; i++) {
    const int row0 = m0 + wm * 64 + i * 16 + quad * 4;
    #pragma unroll
    for (int j = 0; j < 4; j++) {
      const int col = n0 + wn * 64 + j * 16 + lm;
      const float bv = bias[col];
      #pragma unroll
      for (int r = 0; r < 4; r++) {
        const size_t idx = (size_t)(row0 + r) * DD + col;
        outp[idx] = acc[i][j][r] + bv + resid[idx];
      }
    }
  }
}

// ---------------- fp8 PV GEMM: 256 thr, 128x128 tiles, BK=64, XOR-swizzled LDS ----------------
// LDS chunk slot c at row r holds global 16B-chunk c ^ ((r>>1)&3) (de-conflicts 64B-stride reads)
// MODE 3: bf16 out scaled by 1/lsum[row]; MODE 4: fp32 partial, K-range by blockIdx.z
template <int MODE>
__launch_bounds__(256, 3)
__global__ void gemm_fp8_kernel(const u8* __restrict__ A, const u8* __restrict__ BT,
                                int K, int lda, int ldb, void* __restrict__ outp,
                                const float* __restrict__ lsum) {
  __shared__ __align__(16) u8 As[128 * 64];
  __shared__ __align__(16) u8 Bs[128 * 64];
  const int m0 = blockIdx.x * 128, n0 = blockIdx.y * 128;
  const int tid = threadIdx.x;
  const int w = tid >> 6, lane = tid & 63, lm = lane & 15, quad = lane >> 4;
  const int wm = w & 1, wn = w >> 1;
  f32x4 acc[4][4] = {};
  const int srow = tid >> 2;                                    // 0..63
  const int scol = ((tid & 3) ^ ((srow >> 1) & 3)) * 16;        // swizzled global chunk
  const size_t kbase = (MODE == 4) ? (size_t)blockIdx.z * (size_t)K : 0;
  const u8* Ag = A + (size_t)(m0 + srow) * lda + kbase + scol;
  const u8* Bg = BT + (size_t)(n0 + srow) * ldb + kbase + scol;
  u8* Al = As + w * 1024;
  u8* Bl = Bs + w * 1024;
  const size_t ars = (size_t)64 * lda;
  const size_t brs = (size_t)64 * ldb;
  const int swz = (lm >> 1) & 3;
  const int off8 = (quad & 1) * 8;
  const int cg0 = quad >> 1;
  for (int kk = 0; kk < K; kk += 64) {
    const u8* ag = Ag + kk;
    const u8* bg = Bg + kk;
    gload16(ag, Al);
    gload16(ag + ars, Al + 4096);
    gload16(bg, Bl);
    gload16(bg + brs, Bl + 4096);
    __syncthreads();
    #pragma unroll
    for (int kk2 = 0; kk2 < 64; kk2 += 32) {
      const int csel = ((cg0 + (kk2 >> 4)) ^ swz) * 16 + off8;
      long af[4], bfr[4];
      #pragma unroll
      for (int i = 0; i < 4; i++)
        af[i] = *(const long*)&As[(wm * 64 + i * 16 + lm) * 64 + csel];
      #pragma unroll
      for (int j = 0; j < 4; j++)
        bfr[j] = *(const long*)&Bs[(wn * 64 + j * 16 + lm) * 64 + csel];
      #pragma unroll
      for (int i = 0; i < 4; i++)
        #pragma unroll
        for (int j = 0; j < 4; j++)
          acc[i][j] = __builtin_amdgcn_mfma_f32_16x16x32_fp8_fp8(af[i], bfr[j], acc[i][j], 0, 0, 0);
    }
    __syncthreads();
  }
  #pragma unroll
  for (int i = 0; i < 4; i++) {
    const int row0 = m0 + wm * 64 + i * 16 + quad * 4;
    float li[4];
    if (MODE == 3) {
      #pragma unroll
      for (int r = 0; r < 4; r++) li[r] = 1.0f / lsum[row0 + r];
    }
    #pragma unroll
    for (int j = 0; j < 4; j++) {
      const int col = n0 + wn * 64 + j * 16 + lm;
      if (MODE == 3) {
        #pragma unroll
        for (int r = 0; r < 4; r++)
          ((u16*)outp)[(size_t)(row0 + r) * DD + col] = f2bf(acc[i][j][r] * li[r]);
      } else {
        float* po = (float*)outp + (size_t)blockIdx.z * NTOK * DD;
        #pragma unroll
        for (int r = 0; r < 4; r++)
          po[(size_t)(row0 + r) * DD + col] = acc[i][j][r];
      }
    }
  }
}

// ---------------- split-K PV reduce (4 parts): attnb = (sum parts) / lsum ----------------
__global__ void pv_reduce_kernel(const float* __restrict__ part, const float* __restrict__ lsum,
                                 u16* __restrict__ attnb) {
  const int idx = blockIdx.x * 256 + threadIdx.x;
  const int row = idx >> 7;
  const int c4 = (idx & 127) << 2;
  const float* p = part + (size_t)row * DD + c4;
  const size_t stride = (size_t)NTOK * DD;
  float4 a = *(const float4*)(p);
  float4 b = *(const float4*)(p + stride);
  float4 c = *(const float4*)(p + 2 * stride);
  float4 d = *(const float4*)(p + 3 * stride);
  const float inv = 1.0f / lsum[row];
  ushort4 o;
  o.x = f2bf((a.x + b.x + c.x + d.x) * inv);
  o.y = f2bf((a.y + b.y + c.y + d.y) * inv);
  o.z = f2bf((a.z + b.z + c.z + d.z) * inv);
  o.w = f2bf((a.w + b.w + c.w + d.w) * inv);
  *(ushort4*)(attnb + (size_t)row * DD + c4) = o;
}

// ---------------- scores: 128 q-rows x 512-key chunk per block, 1024 thr ----------------
// q pre-scaled by SCL*LOG2E; max-free chunk softmax; fp8 P store; XOR-swizzled LDS staging
__launch_bounds__(1024, 4)
__global__ void scores_kernel(const u16* __restrict__ qb, const u16* __restrict__ kb,
                              u8* __restrict__ P8, float* __restrict__ lsum) {
  __shared__ __align__(16) u16 As[128 * 32];   // 8 KB
  __shared__ __align__(16) u16 Bs[512 * 32];   // 32 KB
  __shared__ float hS[8][128], hP[8][128], hZ[128];
  const int m0 = blockIdx.x * 128;
  const int c = blockIdx.y;
  const int tid = threadIdx.x;
  const int w = tid >> 6, lane = tid & 63, lm = lane & 15, quad = lane >> 4;
  const int mt = w & 1, wsl = w >> 1;
  f32x4 s[4][4] = {};
  const int srA = tid >> 2;
  const int scA = ((tid & 3) ^ ((srA >> 1) & 3)) * 16;   // swizzled global chunk
  const char* Qg = (const char*)qb + ((size_t)(m0 + srA) * DD) * 2 + scA;
  const char* Kg = (const char*)kb + ((size_t)(c * CHK + srA) * DD) * 2 + scA;
  char* Al = (char*)As + w * 1024;
  char* Bl = (char*)Bs + w * 1024;
  const int swz = (lm >> 1) & 3;
  for (int kk = 0; kk < DD; kk += 32) {
    if (tid < 512) gload16(Qg + kk * 2, Al);
    gload16(Kg + kk * 2, Bl);
    gload16(Kg + kk * 2 + (size_t)256 * DD * 2, Bl + 16384);
    __syncthreads();
    bf16x8 af[4], bfr[4];
    #pragma unroll
    for (int i = 0; i < 4; i++)
      af[i] = *(const bf16x8*)&As[(mt * 64 + i * 16 + lm) * 32 + (quad ^ swz) * 8];
    #pragma unroll
    for (int j = 0; j < 4; j++)
      bfr[j] = *(const bf16x8*)&Bs[(wsl * 64 + j * 16 + lm) * 32 + (quad ^ swz) * 8];
    #pragma unroll
    for (int i = 0; i < 4; i++)
      #pragma unroll
      for (int j = 0; j < 4; j++)
        s[i][j] = __builtin_amdgcn_mfma_f32_16x16x32_bf16(af[i], bfr[j], s[i][j], 0, 0, 0);
    __syncthreads();
  }
  // ---- phase A: e = exp2(s*log2e); per-wave (64-col) partial row sums (DPP) ----
  #pragma unroll
  for (int i = 0; i < 4; i++) {
    #pragma unroll
    for (int reg = 0; reg < 4; reg++) {
      float z = 0.f;
      #pragma unroll
      for (int j = 0; j < 4; j++) {
        float e = exp2f(s[i][j][reg]);
        s[i][j][reg] = e;
        z += e;
      }
      z = rowsum16(z);
      if (lm == 0) hS[wsl][mt * 64 + i * 16 + quad * 4 + reg] = z;
    }
  }
  __syncthreads();
  // ---- phase B: row totals -> hZ = LOG2E / Z ----
  if (tid < 128) {
    float t = 0.f;
    #pragma unroll
    for (int w2 = 0; w2 < 8; w2++) t += hS[w2][tid];
    hZ[tid] = LOG2E / t;
  }
  __syncthreads();
  // ---- phase C: p = exp2(e * LOG2E/Z); fp8 packed permuted store; partial l ----
  #pragma unroll
  for (int i = 0; i < 4; i++) {
    #pragma unroll
    for (int reg = 0; reg < 4; reg++) {
      const int rl = mt * 64 + i * 16 + quad * 4 + reg;
      const float iz = hZ[rl];
      const float p0 = exp2f(s[i][0][reg] * iz);
      const float p1 = exp2f(s[i][1][reg] * iz);
      const float p2 = exp2f(s[i][2][reg] * iz);
      const float p3 = exp2f(s[i][3][reg] * iz);
      float zp = (p0 + p1) + (p2 + p3);
      zp = rowsum16(zp);
      if (lm == 0) hP[wsl][rl] = zp;
      uint32_t o = __builtin_amdgcn_cvt_pk_fp8_f32(p0, p1, 0, false);
      o = __builtin_amdgcn_cvt_pk_fp8_f32(p2, p3, o, true);
      *(uint32_t*)(P8 + (size_t)(m0 + rl) * NTOK + c * CHK + wsl * 64 + lm * 4) = o;
    }
  }
  __syncthreads();
  if (tid < 128) {
    float t = 0.f;
    #pragma unroll
    for (int w2 = 0; w2 < 8; w2++) t += hP[w2][tid];
    atomicAdd(&lsum[m0 + tid], t);
  }
}

// ---------------- cls row (exact fp32) ----------------
__global__ void cls_u_kernel(const float* __restrict__ Wk, const float* __restrict__ bk,
                             const float* __restrict__ q0g, float* __restrict__ uc) {
  __shared__ float q0[512];
  const int tid = threadIdx.x;
  q0[tid] = q0g[tid];
  q0[tid + 256] = q0g[tid + 256];
  __syncthreads();
  if (blockIdx.x < 8) {
    const int c = blockIdx.x * 64 + (tid >> 2), ii = tid & 3;
    float acc = 0.f;
    #pragma unroll 8
    for (int j = ii; j < 512; j += 4) acc += Wk[(size_t)c * 512 + j] * q0[j];
    acc += __shfl_xor(acc, 1, 64);
    acc += __shfl_xor(acc, 2, 64);
    if (ii == 0) uc[c] = acc;
  } else if (tid < 64) {
    float acc = 0.f;
    #pragma unroll 8
    for (int j = tid; j < 512; j += 64) acc += bk[j] * q0[j];
    #pragma unroll
    for (int off = 1; off < 64; off <<= 1) acc += __shfl_xor(acc, off, 64);
    if (tid == 0) uc[512] = acc;
  }
}

__global__ void cls_scores_kernel(const float* __restrict__ x, const float* __restrict__ uc,
                                  float* __restrict__ s0) {
  __shared__ float u[512];
  __shared__ float c0s;
  int tid = threadIdx.x;  // 256
  for (int i = tid; i < 512; i += 256) u[i] = uc[i];
  if (tid == 0) c0s = uc[512];
  __syncthreads();
  int rowg = blockIdx.x * 32 + (tid >> 3);
  int ii = tid & 7;
  const float* xr = x + rowg * 512;
  float acc = 0.f;
  for (int i = ii; i < 512; i += 8) acc += xr[i] * u[i];
  acc += __shfl_xor(acc, 1, 64);
  acc += __shfl_xor(acc, 2, 64);
  acc += __shfl_xor(acc, 4, 64);
  if (ii == 0) s0[rowg] = (acc + c0s) * SCL;
}

__global__ void cls_softmax_kernel(const float* __restrict__ s0, float* __restrict__ out) {
  int tid = threadIdx.x;  // 1024 = 16 waves, wave w = chunk w
  int w = tid >> 6, lane = tid & 63;
  const float* sc = s0 + w * 512;
  float v[8];
  float m = -1e30f;
  #pragma unroll
  for (int j = 0; j < 8; j++) { v[j] = sc[lane * 8 + j]; m = fmaxf(m, v[j]); }
  for (int off = 1; off < 64; off <<= 1) m = fmaxf(m, __shfl_xor(m, off, 64));
  float z = 0.f;
  #pragma unroll
  for (int j = 0; j < 8; j++) { v[j] = expf(v[j] - m); z += v[j]; }
  for (int off = 1; off < 64; off <<= 1) z += __shfl_xor(z, off, 64);
  float invz = 1.f / z;
  float l = 0.f;
  #pragma unroll
  for (int j = 0; j < 8; j++) { v[j] = expf(v[j] * invz); l += v[j]; }
  for (int off = 1; off < 64; off <<= 1) l += __shfl_xor(l, off, 64);
  __shared__ float lw[16];
  if (lane == 0) lw[w] = l;
  __syncthreads();
  float L = 0.f;
  for (int i = 0; i < 16; i++) L += lw[i];
  float invL = 1.f / L;
  #pragma unroll
  for (int j = 0; j < 8; j++) out[w * 512 + lane * 8 + j] = v[j] * invL;
}

extern "C" void kernel_launch(void* const* d_in, const int* in_sizes, int n_in,
                              void* d_out, int out_size, void* d_ws, size_t ws_size,
                              hipStream_t stream) {
  const float* x  = (const float*)d_in[0];
  const float* Wq = (const float*)d_in[1];
  const float* bq = (const float*)d_in[2];
  const float* Wk = (const float*)d_in[3];
  const float* bk = (const float*)d_in[4];
  const float* Wv = (const float*)d_in[5];
  const float* bv = (const float*)d_in[6];
  const float* Wo = (const float*)d_in[7];
  const float* bo = (const float*)d_in[8];
  float* out = (float*)d_out;

  char* ws = (char*)d_ws;
  u16* xb    = (u16*)(ws);                  // 8 MB
  u16* Wall  = (u16*)(ws + 8388608);        // 1.5 MB
  u16* WoT   = (u16*)(ws + 9961472);        // 512 KB
  u16* qb    = (u16*)(ws + 10485760);       // 8 MB (pre-scaled by SCL*LOG2E)
  u16* kb    = (u16*)(ws + 18874368);       // 8 MB
  u8*  vT8   = (u8*)(ws + 27262976);        // 4 MB fp8 (token-permuted)
  u16* attnb = (u16*)(ws + 35651584);       // 8 MB
  float* q0g = (float*)(ws + 44040192);     // 512 f
  float* uc  = (float*)(ws + 44042240);     // 513 f
  float* s0  = (float*)(ws + 44048384);     // 8192 f
  float* lsum= (float*)(ws + 44081152);     // 8192 f
  u8*  P8    = (u8*)(ws + 44113920);        // 64 MB fp8 (token-permuted cols)
  float* part= (float*)(ws + 111222784);    // 4 x 16 MB
  const size_t need_full = 111222784ULL + (size_t)KSPLIT * NTOK * DD * 4ULL;

  prep_kernel<<<5122, 256, 0, stream>>>(x, Wq, Wk, Wv, Wo, bq, xb, Wall, WoT, lsum, q0g);

  qkv_kernel<<<dim3(NTOK / 128, 12), 256, 0, stream>>>(xb, Wall, bq, bk, bv, qb, kb, vT8);

  scores_kernel<<<dim3(NTOK / 128, NCH), 1024, 0, stream>>>(qb, kb, P8, lsum);

  if (ws_size >= need_full) {
    gemm_fp8_kernel<4><<<dim3(NTOK / 128, DD / 128, KSPLIT), 256, 0, stream>>>(
        P8, vT8, KLEN, NTOK, NTOK, part, nullptr);
    pv_reduce_kernel<<<NTOK * DD / 4 / 256, 256, 0, stream>>>(part, lsum, attnb);
  } else {
    gemm_fp8_kernel<3><<<dim3(NTOK / 128, DD / 128), 256, 0, stream>>>(
        P8, vT8, NTOK, NTOK, NTOK, attnb, lsum);
  }

  outproj_kernel<<<dim3(NTOK / 128, DD / 128), 256, 0, stream>>>(attnb, WoT, bo, out, x);

  cls_u_kernel<<<9, 256, 0, stream>>>(Wk, bk, q0g, uc);
  cls_scores_kernel<<<NTOK / 32, 256, 0, stream>>>(x, uc, s0);
  cls_softmax_kernel<<<1, 1024, 0, stream>>>(s0, out + (size_t)NTOK * DD);
}

// Round 9
// 330.661 us; speedup vs baseline: 3.0781x; 1.0501x over previous
//
#include <hip/hip_runtime.h>
#include <stdint.h>

typedef unsigned short u16;
typedef uint8_t u8;
typedef __bf16 bf16x8 __attribute__((ext_vector_type(8)));
typedef float f32x4 __attribute__((ext_vector_type(4)));

#define NTOK 8192
#define DD 512
#define CHK 512
#define NCH 16
#define KSPLIT 4
#define KLEN 2048
#define LOG2E 1.4426950408889634f
#define SCL 0.044194173824159216f          // 1/sqrt(512)
#define SCLL 0.063762069130835270f         // SCL * LOG2E

__device__ __forceinline__ u16 f2bf(float f) {
  union { float f; uint32_t u; } v; v.f = f;
  uint32_t r = v.u + 0x7FFFu + ((v.u >> 16) & 1u);
  return (u16)(r >> 16);
}

// DPP-based 16-lane (row) sum: stays on VALU pipe, avoids LDS-pipe shuffles.
template <int CTRL>
__device__ __forceinline__ float dppadd(float x) {
  int y = __builtin_amdgcn_update_dpp(0, __float_as_int(x), CTRL, 0xF, 0xF, true);
  return x + __int_as_float(y);
}
__device__ __forceinline__ float rowsum16(float x) {
  x = dppadd<0xB1>(x);    // quad_perm(1,0,3,2)
  x = dppadd<0x4E>(x);    // quad_perm(2,3,0,1)
  x = dppadd<0x141>(x);   // row_half_mirror
  x = dppadd<0x140>(x);   // row_mirror
  return x;
}

// async global->LDS, 16B per lane. LDS dest is wave-uniform base + lane*16.
typedef const __attribute__((address_space(1))) unsigned int* gas_t;
typedef __attribute__((address_space(3))) unsigned int* las_t;
__device__ __forceinline__ void gload16(const void* g, void* l) {
  __builtin_amdgcn_global_load_lds((gas_t)g, (las_t)l, 16, 0, 0);
}

// token permutation within 64-groups (applied to both P cols and vT rows; PV
// contracts over the same permuted coordinate so results are unchanged)
__device__ __forceinline__ int permtok(int t) {
  return (t & ~63) | (((t & 15) << 2) | ((t >> 4) & 3));
}

// ---------------- prep: cast x->bf16 (+zero lsum), transpose 4 weights, cls q0 ----------------
__global__ void prep_kernel(const float* __restrict__ x, const float* __restrict__ Wq,
                            const float* __restrict__ Wk, const float* __restrict__ Wv,
                            const float* __restrict__ Wo, const float* __restrict__ bq,
                            u16* __restrict__ xb, u16* __restrict__ Wall, u16* __restrict__ WoT,
                            float* __restrict__ lsum, float* __restrict__ q0g) {
  __shared__ float t[32][33];
  const int bid = blockIdx.x;
  const int tid = threadIdx.x;
  if (bid < 4096) {
    int i = bid * 256 + tid;
    if (bid < 32) lsum[bid * 256 + tid] = 0.f;
    float4 v = ((const float4*)x)[i];
    ushort4 o;
    o.x = f2bf(v.x); o.y = f2bf(v.y); o.z = f2bf(v.z); o.w = f2bf(v.w);
    ((ushort4*)xb)[i] = o;
  } else if (bid < 5120) {
    const int tt = bid - 4096;
    const int z = tt >> 8, idx = tt & 255;
    const float* W; u16* WT;
    if (z == 0)      { W = Wq; WT = Wall; }
    else if (z == 1) { W = Wk; WT = Wall + 512 * 512; }
    else if (z == 2) { W = Wv; WT = Wall + 2 * 512 * 512; }
    else             { W = Wo; WT = WoT; }
    const int n0 = (idx & 15) * 32, k0 = (idx >> 4) * 32;
    const int tx = tid & 31, ty = tid >> 5;  // 32 x 8
    #pragma unroll
    for (int i = 0; i < 4; i++)
      t[ty + 8 * i][tx] = W[(k0 + ty + 8 * i) * DD + n0 + tx];
    __syncthreads();
    #pragma unroll
    for (int i = 0; i < 4; i++)
      WT[(n0 + ty + 8 * i) * DD + k0 + tx] = f2bf(t[tx][ty + 8 * i]);
  } else {
    const int c = (bid - 5120) * 256 + tid;
    float acc = bq[c];
    #pragma unroll 8
    for (int i = 0; i < 512; i++) acc += x[i] * Wq[i * 512 + c];
    q0g[c] = acc;
  }
}

// ---------------- fused q/k/v projection: 256 thr, 128x128 tiles ----------------
// by: 0..11; which = by>>2 (0=q fp8 raw, 1=k fp8 raw, 2=v transposed+permuted fp8)
__launch_bounds__(256, 3)
__global__ void qkv_kernel(const u16* __restrict__ A, const u16* __restrict__ Wall,
                           const float* __restrict__ bq, const float* __restrict__ bk,
                           const float* __restrict__ bv, u8* __restrict__ qb8,
                           u8* __restrict__ kb8, u8* __restrict__ vT8) {
  __shared__ __align__(16) u16 As[128 * 32];
  __shared__ __align__(16) u16 Bs[128 * 32];
  const int m0 = blockIdx.x * 128;
  const int n0g = blockIdx.y * 128;
  const int which = blockIdx.y >> 2;
  const int n0 = n0g & 511;
  const int tid = threadIdx.x;
  const int w = tid >> 6, lane = tid & 63, lm = lane & 15, quad = lane >> 4;
  const int wm = w & 1, wn = w >> 1;
  f32x4 acc[4][4] = {};
  const int soff = tid * 16;
  const int srow = soff >> 6;
  const int scol = soff & 63;
  const char* Ag = (const char*)A + ((size_t)(m0 + srow) * DD) * 2 + scol;
  const char* Bg = (const char*)Wall + ((size_t)(n0g + srow) * DD) * 2 + scol;
  char* Al = (char*)As + w * 1024;
  char* Bl = (char*)Bs + w * 1024;
  const size_t rs = (size_t)64 * DD * 2;
  for (int kk = 0; kk < DD; kk += 32) {
    const char* ag = Ag + (size_t)kk * 2;
    const char* bg = Bg + (size_t)kk * 2;
    gload16(ag, Al);
    gload16(ag + rs, Al + 4096);
    gload16(bg, Bl);
    gload16(bg + rs, Bl + 4096);
    __syncthreads();
    bf16x8 af[4], bfr[4];
    #pragma unroll
    for (int i = 0; i < 4; i++) af[i] = *(const bf16x8*)&As[(wm * 64 + i * 16 + lm) * 32 + quad * 8];
    #pragma unroll
    for (int j = 0; j < 4; j++) bfr[j] = *(const bf16x8*)&Bs[(wn * 64 + j * 16 + lm) * 32 + quad * 8];
    #pragma unroll
    for (int i = 0; i < 4; i++)
      #pragma unroll
      for (int j = 0; j < 4; j++)
        acc[i][j] = __builtin_amdgcn_mfma_f32_16x16x32_bf16(af[i], bfr[j], acc[i][j], 0, 0, 0);
    __syncthreads();
  }
  const float* bias = (which == 0) ? bq : (which == 1) ? bk : bv;
  #pragma unroll
  for (int i = 0; i < 4; i++) {
    const int row0 = m0 + wm * 64 + i * 16 + quad * 4;
    #pragma unroll
    for (int j = 0; j < 4; j++) {
      const int col = n0 + wn * 64 + j * 16 + lm;
      const float bv_ = bias[col];
      if (which == 2) {
        #pragma unroll
        for (int r = 0; r < 4; r++) {
          const float val = acc[i][j][r] + bv_;
          uint32_t pk = __builtin_amdgcn_cvt_pk_fp8_f32(val, val, 0, false);
          vT8[(size_t)col * NTOK + permtok(row0 + r)] = (u8)(pk & 0xFF);
        }
      } else {
        u8* dst = (which == 0) ? qb8 : kb8;
        #pragma unroll
        for (int r = 0; r < 4; r++) {
          const float val = acc[i][j][r] + bv_;
          uint32_t pk = __builtin_amdgcn_cvt_pk_fp8_f32(val, val, 0, false);
          dst[(size_t)(row0 + r) * DD + col] = (u8)(pk & 0xFF);
        }
      }
    }
  }
}

// ---------------- out projection: 256 thr, 128x128 tiles, bf16 in / fp32+resid out ----------------
__launch_bounds__(256, 3)
__global__ void outproj_kernel(const u16* __restrict__ A, const u16* __restrict__ BT,
                               const float* __restrict__ bias, float* __restrict__ outp,
                               const float* __restrict__ resid) {
  __shared__ __align__(16) u16 As[128 * 32];
  __shared__ __align__(16) u16 Bs[128 * 32];
  const int m0 = blockIdx.x * 128, n0 = blockIdx.y * 128;
  const int tid = threadIdx.x;
  const int w = tid >> 6, lane = tid & 63, lm = lane & 15, quad = lane >> 4;
  const int wm = w & 1, wn = w >> 1;
  f32x4 acc[4][4] = {};
  const int soff = tid * 16;
  const int srow = soff >> 6;
  const int scol = soff & 63;
  const char* Ag = (const char*)A + ((size_t)(m0 + srow) * DD) * 2 + scol;
  const char* Bg = (const char*)BT + ((size_t)(n0 + srow) * DD) * 2 + scol;
  char* Al = (char*)As + w * 1024;
  char* Bl = (char*)Bs + w * 1024;
  const size_t rs = (size_t)64 * DD * 2;
  for (int kk = 0; kk < DD; kk += 32) {
    const char* ag = Ag + (size_t)kk * 2;
    const char* bg = Bg + (size_t)kk * 2;
    gload16(ag, Al);
    gload16(ag + rs, Al + 4096);
    gload16(bg, Bl);
    gload16(bg + rs, Bl + 4096);
    __syncthreads();
    bf16x8 af[4], bfr[4];
    #pragma unroll
    for (int i = 0; i < 4; i++) af[i] = *(const bf16x8*)&As[(wm * 64 + i * 16 + lm) * 32 + quad * 8];
    #pragma unroll
    for (int j = 0; j < 4; j++) bfr[j] = *(const bf16x8*)&Bs[(wn * 64 + j * 16 + lm) * 32 + quad * 8];
    #pragma unroll
    for (int i = 0; i < 4; i++)
      #pragma unroll
      for (int j = 0; j < 4; j++)
        acc[i][j] = __builtin_amdgcn_mfma_f32_16x16x32_bf16(af[i], bfr[j], acc[i][j], 0, 0, 0);
    __syncthreads();
  }
  #pragma unroll
  for (int i = 0; i < 4; i++) {
    const int row0 = m0 + wm * 64 + i * 16 + quad * 4;
    #pragma unroll
    for (int j = 0; j < 4; j++) {
      const int col = n0 + wn * 64 + j * 16 + lm;
      const float bv = bias[col];
      #pragma unroll
      for (int r = 0; r < 4; r++) {
        const size_t idx = (size_t)(row0 + r) * DD + col;
        outp[idx] = acc[i][j][r] + bv + resid[idx];
      }
    }
  }
}

// ---------------- fp8 PV GEMM: 256 thr, 128x128 tiles, BK=64, XOR-swizzled LDS ----------------
// MODE 3: bf16 out scaled by 1/lsum[row]; MODE 4: fp32 partial, K-range by blockIdx.z
template <int MODE>
__launch_bounds__(256, 3)
__global__ void gemm_fp8_kernel(const u8* __restrict__ A, const u8* __restrict__ BT,
                                int K, int lda, int ldb, void* __restrict__ outp,
                                const float* __restrict__ lsum) {
  __shared__ __align__(16) u8 As[128 * 64];
  __shared__ __align__(16) u8 Bs[128 * 64];
  const int m0 = blockIdx.x * 128, n0 = blockIdx.y * 128;
  const int tid = threadIdx.x;
  const int w = tid >> 6, lane = tid & 63, lm = lane & 15, quad = lane >> 4;
  const int wm = w & 1, wn = w >> 1;
  f32x4 acc[4][4] = {};
  const int srow = tid >> 2;                                    // 0..63
  const int scol = ((tid & 3) ^ ((srow >> 1) & 3)) * 16;        // swizzled global chunk
  const size_t kbase = (MODE == 4) ? (size_t)blockIdx.z * (size_t)K : 0;
  const u8* Ag = A + (size_t)(m0 + srow) * lda + kbase + scol;
  const u8* Bg = BT + (size_t)(n0 + srow) * ldb + kbase + scol;
  u8* Al = As + w * 1024;
  u8* Bl = Bs + w * 1024;
  const size_t ars = (size_t)64 * lda;
  const size_t brs = (size_t)64 * ldb;
  const int swz = (lm >> 1) & 3;
  const int off8 = (quad & 1) * 8;
  const int cg0 = quad >> 1;
  for (int kk = 0; kk < K; kk += 64) {
    const u8* ag = Ag + kk;
    const u8* bg = Bg + kk;
    gload16(ag, Al);
    gload16(ag + ars, Al + 4096);
    gload16(bg, Bl);
    gload16(bg + brs, Bl + 4096);
    __syncthreads();
    #pragma unroll
    for (int kk2 = 0; kk2 < 64; kk2 += 32) {
      const int csel = ((cg0 + (kk2 >> 4)) ^ swz) * 16 + off8;
      long af[4], bfr[4];
      #pragma unroll
      for (int i = 0; i < 4; i++)
        af[i] = *(const long*)&As[(wm * 64 + i * 16 + lm) * 64 + csel];
      #pragma unroll
      for (int j = 0; j < 4; j++)
        bfr[j] = *(const long*)&Bs[(wn * 64 + j * 16 + lm) * 64 + csel];
      #pragma unroll
      for (int i = 0; i < 4; i++)
        #pragma unroll
        for (int j = 0; j < 4; j++)
          acc[i][j] = __builtin_amdgcn_mfma_f32_16x16x32_fp8_fp8(af[i], bfr[j], acc[i][j], 0, 0, 0);
    }
    __syncthreads();
  }
  #pragma unroll
  for (int i = 0; i < 4; i++) {
    const int row0 = m0 + wm * 64 + i * 16 + quad * 4;
    float li[4];
    if (MODE == 3) {
      #pragma unroll
      for (int r = 0; r < 4; r++) li[r] = 1.0f / lsum[row0 + r];
    }
    #pragma unroll
    for (int j = 0; j < 4; j++) {
      const int col = n0 + wn * 64 + j * 16 + lm;
      if (MODE == 3) {
        #pragma unroll
        for (int r = 0; r < 4; r++)
          ((u16*)outp)[(size_t)(row0 + r) * DD + col] = f2bf(acc[i][j][r] * li[r]);
      } else {
        float* po = (float*)outp + (size_t)blockIdx.z * NTOK * DD;
        #pragma unroll
        for (int r = 0; r < 4; r++)
          po[(size_t)(row0 + r) * DD + col] = acc[i][j][r];
      }
    }
  }
}

// ---------------- split-K PV reduce (4 parts): attnb = (sum parts) / lsum ----------------
__global__ void pv_reduce_kernel(const float* __restrict__ part, const float* __restrict__ lsum,
                                 u16* __restrict__ attnb) {
  const int idx = blockIdx.x * 256 + threadIdx.x;
  const int row = idx >> 7;
  const int c4 = (idx & 127) << 2;
  const float* p = part + (size_t)row * DD + c4;
  const size_t stride = (size_t)NTOK * DD;
  float4 a = *(const float4*)(p);
  float4 b = *(const float4*)(p + stride);
  float4 c = *(const float4*)(p + 2 * stride);
  float4 d = *(const float4*)(p + 3 * stride);
  const float inv = 1.0f / lsum[row];
  ushort4 o;
  o.x = f2bf((a.x + b.x + c.x + d.x) * inv);
  o.y = f2bf((a.y + b.y + c.y + d.y) * inv);
  o.z = f2bf((a.z + b.z + c.z + d.z) * inv);
  o.w = f2bf((a.w + b.w + c.w + d.w) * inv);
  *(ushort4*)(attnb + (size_t)row * DD + c4) = o;
}

// ---------------- scores: fp8 QK^T, 128 q-rows x 512-key chunk, 1024 thr, BK=64 ----------------
// q/k raw fp8; phase A applies SCLL inside exp2; fp8 P store; XOR-swizzled LDS
__launch_bounds__(1024, 4)
__global__ void scores_kernel(const u8* __restrict__ qb8, const u8* __restrict__ kb8,
                              u8* __restrict__ P8, float* __restrict__ lsum) {
  __shared__ __align__(16) u8 As[128 * 64];   // 8 KB
  __shared__ __align__(16) u8 Bs[512 * 64];   // 32 KB
  __shared__ float hS[8][128], hP[8][128], hZ[128];
  const int m0 = blockIdx.x * 128;
  const int c = blockIdx.y;
  const int tid = threadIdx.x;
  const int w = tid >> 6, lane = tid & 63, lm = lane & 15, quad = lane >> 4;
  const int mt = w & 1, wsl = w >> 1;
  f32x4 s[4][4] = {};
  // A staging (tid<512): 128 rows x 64B; B staging: 2 calls x 256 rows x 64B
  const int srA = tid >> 2;                                   // A: 0..127 ; B: 0..255
  const int scS = ((tid & 3) ^ ((srA >> 1) & 3)) * 16;        // swizzle (r*256 preserves (row>>1)&3)
  const u8* Qg = qb8 + (size_t)(m0 + srA) * DD + scS;
  const u8* Kg = kb8 + (size_t)(c * CHK + srA) * DD + scS;
  u8* Al = As + w * 1024;
  u8* Bl = Bs + w * 1024;
  const int swz = (lm >> 1) & 3;
  const int off8 = (quad & 1) * 8;
  const int cg0 = quad >> 1;
  for (int kk = 0; kk < DD; kk += 64) {
    if (tid < 512) gload16(Qg + kk, Al);
    gload16(Kg + kk, Bl);
    gload16(Kg + kk + (size_t)256 * DD, Bl + 16384);
    __syncthreads();
    #pragma unroll
    for (int kk2 = 0; kk2 < 64; kk2 += 32) {
      const int csel = ((cg0 + (kk2 >> 4)) ^ swz) * 16 + off8;
      long af[4], bfr[4];
      #pragma unroll
      for (int i = 0; i < 4; i++)
        af[i] = *(const long*)&As[(mt * 64 + i * 16 + lm) * 64 + csel];
      #pragma unroll
      for (int j = 0; j < 4; j++)
        bfr[j] = *(const long*)&Bs[(wsl * 64 + j * 16 + lm) * 64 + csel];
      #pragma unroll
      for (int i = 0; i < 4; i++)
        #pragma unroll
        for (int j = 0; j < 4; j++)
          s[i][j] = __builtin_amdgcn_mfma_f32_16x16x32_fp8_fp8(af[i], bfr[j], s[i][j], 0, 0, 0);
    }
    __syncthreads();
  }
  // ---- phase A: e = exp2(s_raw * SCL*LOG2E); per-wave (64-col) partial row sums (DPP) ----
  #pragma unroll
  for (int i = 0; i < 4; i++) {
    #pragma unroll
    for (int reg = 0; reg < 4; reg++) {
      float z = 0.f;
      #pragma unroll
      for (int j = 0; j < 4; j++) {
        float e = exp2f(s[i][j][reg] * SCLL);
        s[i][j][reg] = e;
        z += e;
      }
      z = rowsum16(z);
      if (lm == 0) hS[wsl][mt * 64 + i * 16 + quad * 4 + reg] = z;
    }
  }
  __syncthreads();
  // ---- phase B: row totals -> hZ = LOG2E / Z ----
  if (tid < 128) {
    float t = 0.f;
    #pragma unroll
    for (int w2 = 0; w2 < 8; w2++) t += hS[w2][tid];
    hZ[tid] = LOG2E / t;
  }
  __syncthreads();
  // ---- phase C: p = exp2(e * LOG2E/Z); fp8 packed permuted store; partial l ----
  #pragma unroll
  for (int i = 0; i < 4; i++) {
    #pragma unroll
    for (int reg = 0; reg < 4; reg++) {
      const int rl = mt * 64 + i * 16 + quad * 4 + reg;
      const float iz = hZ[rl];
      const float p0 = exp2f(s[i][0][reg] * iz);
      const float p1 = exp2f(s[i][1][reg] * iz);
      const float p2 = exp2f(s[i][2][reg] * iz);
      const float p3 = exp2f(s[i][3][reg] * iz);
      float zp = (p0 + p1) + (p2 + p3);
      zp = rowsum16(zp);
      if (lm == 0) hP[wsl][rl] = zp;
      uint32_t o = __builtin_amdgcn_cvt_pk_fp8_f32(p0, p1, 0, false);
      o = __builtin_amdgcn_cvt_pk_fp8_f32(p2, p3, o, true);
      *(uint32_t*)(P8 + (size_t)(m0 + rl) * NTOK + c * CHK + wsl * 64 + lm * 4) = o;
    }
  }
  __syncthreads();
  if (tid < 128) {
    float t = 0.f;
    #pragma unroll
    for (int w2 = 0; w2 < 8; w2++) t += hP[w2][tid];
    atomicAdd(&lsum[m0 + tid], t);
  }
}

// ---------------- cls row (exact fp32) ----------------
__global__ void cls_u_kernel(const float* __restrict__ Wk, const float* __restrict__ bk,
                             const float* __restrict__ q0g, float* __restrict__ uc) {
  __shared__ float q0[512];
  const int tid = threadIdx.x;
  q0[tid] = q0g[tid];
  q0[tid + 256] = q0g[tid + 256];
  __syncthreads();
  if (blockIdx.x < 8) {
    const int c = blockIdx.x * 64 + (tid >> 2), ii = tid & 3;
    float acc = 0.f;
    #pragma unroll 8
    for (int j = ii; j < 512; j += 4) acc += Wk[(size_t)c * 512 + j] * q0[j];
    acc += __shfl_xor(acc, 1, 64);
    acc += __shfl_xor(acc, 2, 64);
    if (ii == 0) uc[c] = acc;
  } else if (tid < 64) {
    float acc = 0.f;
    #pragma unroll 8
    for (int j = tid; j < 512; j += 64) acc += bk[j] * q0[j];
    #pragma unroll
    for (int off = 1; off < 64; off <<= 1) acc += __shfl_xor(acc, off, 64);
    if (tid == 0) uc[512] = acc;
  }
}

__global__ void cls_scores_kernel(const float* __restrict__ x, const float* __restrict__ uc,
                                  float* __restrict__ s0) {
  __shared__ float u[512];
  __shared__ float c0s;
  int tid = threadIdx.x;  // 256
  for (int i = tid; i < 512; i += 256) u[i] = uc[i];
  if (tid == 0) c0s = uc[512];
  __syncthreads();
  int rowg = blockIdx.x * 32 + (tid >> 3);
  int ii = tid & 7;
  const float* xr = x + rowg * 512;
  float acc = 0.f;
  for (int i = ii; i < 512; i += 8) acc += xr[i] * u[i];
  acc += __shfl_xor(acc, 1, 64);
  acc += __shfl_xor(acc, 2, 64);
  acc += __shfl_xor(acc, 4, 64);
  if (ii == 0) s0[rowg] = (acc + c0s) * SCL;
}

__global__ void cls_softmax_kernel(const float* __restrict__ s0, float* __restrict__ out) {
  int tid = threadIdx.x;  // 1024 = 16 waves, wave w = chunk w
  int w = tid >> 6, lane = tid & 63;
  const float* sc = s0 + w * 512;
  float v[8];
  float m = -1e30f;
  #pragma unroll
  for (int j = 0; j < 8; j++) { v[j] = sc[lane * 8 + j]; m = fmaxf(m, v[j]); }
  for (int off = 1; off < 64; off <<= 1) m = fmaxf(m, __shfl_xor(m, off, 64));
  float z = 0.f;
  #pragma unroll
  for (int j = 0; j < 8; j++) { v[j] = expf(v[j] - m); z += v[j]; }
  for (int off = 1; off < 64; off <<= 1) z += __shfl_xor(z, off, 64);
  float invz = 1.f / z;
  float l = 0.f;
  #pragma unroll
  for (int j = 0; j < 8; j++) { v[j] = expf(v[j] * invz); l += v[j]; }
  for (int off = 1; off < 64; off <<= 1) l += __shfl_xor(l, off, 64);
  __shared__ float lw[16];
  if (lane == 0) lw[w] = l;
  __syncthreads();
  float L = 0.f;
  for (int i = 0; i < 16; i++) L += lw[i];
  float invL = 1.f / L;
  #pragma unroll
  for (int j = 0; j < 8; j++) out[w * 512 + lane * 8 + j] = v[j] * invL;
}

extern "C" void kernel_launch(void* const* d_in, const int* in_sizes, int n_in,
                              void* d_out, int out_size, void* d_ws, size_t ws_size,
                              hipStream_t stream) {
  const float* x  = (const float*)d_in[0];
  const float* Wq = (const float*)d_in[1];
  const float* bq = (const float*)d_in[2];
  const float* Wk = (const float*)d_in[3];
  const float* bk = (const float*)d_in[4];
  const float* Wv = (const float*)d_in[5];
  const float* bv = (const float*)d_in[6];
  const float* Wo = (const float*)d_in[7];
  const float* bo = (const float*)d_in[8];
  float* out = (float*)d_out;

  char* ws = (char*)d_ws;
  u16* xb    = (u16*)(ws);                  // 8 MB
  u16* Wall  = (u16*)(ws + 8388608);        // 1.5 MB
  u16* WoT   = (u16*)(ws + 9961472);        // 512 KB
  u8*  qb8   = (u8*)(ws + 10485760);        // 4 MB fp8 (raw q)
  u8*  kb8   = (u8*)(ws + 14680064);        // 4 MB fp8 (raw k)
  u8*  vT8   = (u8*)(ws + 18874368);        // 4 MB fp8 (token-permuted)
  u16* attnb = (u16*)(ws + 23068672);       // 8 MB
  float* q0g = (float*)(ws + 31457280);     // 512 f
  float* uc  = (float*)(ws + 31461376);     // 513 f
  float* s0  = (float*)(ws + 31465472);     // 8192 f
  float* lsum= (float*)(ws + 31498240);     // 8192 f
  u8*  P8    = (u8*)(ws + 31531008);        // 64 MB fp8 (token-permuted cols)
  float* part= (float*)(ws + 98639872);     // 4 x 16 MB
  const size_t need_full = 98639872ULL + (size_t)KSPLIT * NTOK * DD * 4ULL;

  prep_kernel<<<5122, 256, 0, stream>>>(x, Wq, Wk, Wv, Wo, bq, xb, Wall, WoT, lsum, q0g);

  qkv_kernel<<<dim3(NTOK / 128, 12), 256, 0, stream>>>(xb, Wall, bq, bk, bv, qb8, kb8, vT8);

  scores_kernel<<<dim3(NTOK / 128, NCH), 1024, 0, stream>>>(qb8, kb8, P8, lsum);

  if (ws_size >= need_full) {
    gemm_fp8_kernel<4><<<dim3(NTOK / 128, DD / 128, KSPLIT), 256, 0, stream>>>(
        P8, vT8, KLEN, NTOK, NTOK, part, nullptr);
    pv_reduce_kernel<<<NTOK * DD / 4 / 256, 256, 0, stream>>>(part, lsum, attnb);
  } else {
    gemm_fp8_kernel<3><<<dim3(NTOK / 128, DD / 128), 256, 0, stream>>>(
        P8, vT8, NTOK, NTOK, NTOK, attnb, lsum);
  }

  outproj_kernel<<<dim3(NTOK / 128, DD / 128), 256, 0, stream>>>(attnb, WoT, bo, out, x);

  cls_u_kernel<<<9, 256, 0, stream>>>(Wk, bk, q0g, uc);
  cls_scores_kernel<<<NTOK / 32, 256, 0, stream>>>(x, uc, s0);
  cls_softmax_kernel<<<1, 1024, 0, stream>>>(s0, out + (size_t)NTOK * DD);
}

// Round 10
// 314.859 us; speedup vs baseline: 3.2325x; 1.0502x over previous
//
#include <hip/hip_runtime.h>
#include <stdint.h>

typedef unsigned short u16;
typedef uint8_t u8;
typedef __bf16 bf16x8 __attribute__((ext_vector_type(8)));
typedef float f32x4 __attribute__((ext_vector_type(4)));
typedef long i64x2 __attribute__((ext_vector_type(2)));

#define NTOK 8192
#define DD 512
#define CHK 512
#define NCH 16
#define KSPLIT 4
#define KLEN 2048
#define LOG2E 1.4426950408889634f
#define SCL 0.044194173824159216f          // 1/sqrt(512)
#define SCLL 0.063762069130835270f         // SCL * LOG2E

__device__ __forceinline__ u16 f2bf(float f) {
  union { float f; uint32_t u; } v; v.f = f;
  uint32_t r = v.u + 0x7FFFu + ((v.u >> 16) & 1u);
  return (u16)(r >> 16);
}

// DPP-based 16-lane (row) sum: stays on VALU pipe, avoids LDS-pipe shuffles.
template <int CTRL>
__device__ __forceinline__ float dppadd(float x) {
  int y = __builtin_amdgcn_update_dpp(0, __float_as_int(x), CTRL, 0xF, 0xF, true);
  return x + __int_as_float(y);
}
__device__ __forceinline__ float rowsum16(float x) {
  x = dppadd<0xB1>(x);    // quad_perm(1,0,3,2)
  x = dppadd<0x4E>(x);    // quad_perm(2,3,0,1)
  x = dppadd<0x141>(x);   // row_half_mirror
  x = dppadd<0x140>(x);   // row_mirror
  return x;
}

// async global->LDS, 16B per lane. LDS dest is wave-uniform base + lane*16.
typedef const __attribute__((address_space(1))) unsigned int* gas_t;
typedef __attribute__((address_space(3))) unsigned int* las_t;
__device__ __forceinline__ void gload16(const void* g, void* l) {
  __builtin_amdgcn_global_load_lds((gas_t)g, (las_t)l, 16, 0, 0);
}

// k/token interleave within 64-groups: 8-byte group c -> (c&3)*2 + (c>>2).
// Makes a lane's two K=32 MFMA fragments (k=q*8.., k=32+q*8..) contiguous 16B.
__device__ __forceinline__ int ilv64(int p) {   // p in 0..63
  const int g = p >> 3;
  return (((g & 3) * 2) + (g >> 2)) * 8 + (p & 7);
}
// composed token permutation for the PV contraction dim (P cols == vT rows)
__device__ __forceinline__ int fperm(int t) {
  const int p = ((t & 15) << 2) | ((t >> 4) & 3);   // permtok within 64
  return (t & ~63) | ilv64(p);
}

// ---------------- prep: cast x->bf16 (+zero lsum), transpose 4 weights, cls q0 ----------------
__global__ void prep_kernel(const float* __restrict__ x, const float* __restrict__ Wq,
                            const float* __restrict__ Wk, const float* __restrict__ Wv,
                            const float* __restrict__ Wo, const float* __restrict__ bq,
                            u16* __restrict__ xb, u16* __restrict__ Wall, u16* __restrict__ WoT,
                            float* __restrict__ lsum, float* __restrict__ q0g) {
  __shared__ float t[32][33];
  const int bid = blockIdx.x;
  const int tid = threadIdx.x;
  if (bid < 4096) {
    int i = bid * 256 + tid;
    if (bid < 32) lsum[bid * 256 + tid] = 0.f;
    float4 v = ((const float4*)x)[i];
    ushort4 o;
    o.x = f2bf(v.x); o.y = f2bf(v.y); o.z = f2bf(v.z); o.w = f2bf(v.w);
    ((ushort4*)xb)[i] = o;
  } else if (bid < 5120) {
    const int tt = bid - 4096;
    const int z = tt >> 8, idx = tt & 255;
    const float* W; u16* WT;
    if (z == 0)      { W = Wq; WT = Wall; }
    else if (z == 1) { W = Wk; WT = Wall + 512 * 512; }
    else if (z == 2) { W = Wv; WT = Wall + 2 * 512 * 512; }
    else             { W = Wo; WT = WoT; }
    const int n0 = (idx & 15) * 32, k0 = (idx >> 4) * 32;
    const int tx = tid & 31, ty = tid >> 5;  // 32 x 8
    #pragma unroll
    for (int i = 0; i < 4; i++)
      t[ty + 8 * i][tx] = W[(k0 + ty + 8 * i) * DD + n0 + tx];
    __syncthreads();
    #pragma unroll
    for (int i = 0; i < 4; i++)
      WT[(n0 + ty + 8 * i) * DD + k0 + tx] = f2bf(t[tx][ty + 8 * i]);
  } else {
    const int c = (bid - 5120) * 256 + tid;
    float acc = bq[c];
    #pragma unroll 8
    for (int i = 0; i < 512; i++) acc += x[i] * Wq[i * 512 + c];
    q0g[c] = acc;
  }
}

// ---------------- fused q/k/v projection: 256 thr, 128x128 tiles ----------------
// by: 0..11; which = by>>2 (0=q fp8 k-interleaved, 1=k fp8 k-interleaved, 2=v fp8 T+fperm)
__launch_bounds__(256, 3)
__global__ void qkv_kernel(const u16* __restrict__ A, const u16* __restrict__ Wall,
                           const float* __restrict__ bq, const float* __restrict__ bk,
                           const float* __restrict__ bv, u8* __restrict__ qb8,
                           u8* __restrict__ kb8, u8* __restrict__ vT8) {
  __shared__ __align__(16) u16 As[128 * 32];
  __shared__ __align__(16) u16 Bs[128 * 32];
  const int m0 = blockIdx.x * 128;
  const int n0g = blockIdx.y * 128;
  const int which = blockIdx.y >> 2;
  const int n0 = n0g & 511;
  const int tid = threadIdx.x;
  const int w = tid >> 6, lane = tid & 63, lm = lane & 15, quad = lane >> 4;
  const int wm = w & 1, wn = w >> 1;
  f32x4 acc[4][4] = {};
  const int soff = tid * 16;
  const int srow = soff >> 6;
  const int scol = soff & 63;
  const char* Ag = (const char*)A + ((size_t)(m0 + srow) * DD) * 2 + scol;
  const char* Bg = (const char*)Wall + ((size_t)(n0g + srow) * DD) * 2 + scol;
  char* Al = (char*)As + w * 1024;
  char* Bl = (char*)Bs + w * 1024;
  const size_t rs = (size_t)64 * DD * 2;
  for (int kk = 0; kk < DD; kk += 32) {
    const char* ag = Ag + (size_t)kk * 2;
    const char* bg = Bg + (size_t)kk * 2;
    gload16(ag, Al);
    gload16(ag + rs, Al + 4096);
    gload16(bg, Bl);
    gload16(bg + rs, Bl + 4096);
    __syncthreads();
    bf16x8 af[4], bfr[4];
    #pragma unroll
    for (int i = 0; i < 4; i++) af[i] = *(const bf16x8*)&As[(wm * 64 + i * 16 + lm) * 32 + quad * 8];
    #pragma unroll
    for (int j = 0; j < 4; j++) bfr[j] = *(const bf16x8*)&Bs[(wn * 64 + j * 16 + lm) * 32 + quad * 8];
    #pragma unroll
    for (int i = 0; i < 4; i++)
      #pragma unroll
      for (int j = 0; j < 4; j++)
        acc[i][j] = __builtin_amdgcn_mfma_f32_16x16x32_bf16(af[i], bfr[j], acc[i][j], 0, 0, 0);
    __syncthreads();
  }
  const float* bias = (which == 0) ? bq : (which == 1) ? bk : bv;
  #pragma unroll
  for (int i = 0; i < 4; i++) {
    const int row0 = m0 + wm * 64 + i * 16 + quad * 4;
    #pragma unroll
    for (int j = 0; j < 4; j++) {
      const int col = n0 + wn * 64 + j * 16 + lm;
      const float bv_ = bias[col];
      if (which == 2) {
        #pragma unroll
        for (int r = 0; r < 4; r++) {
          const float val = acc[i][j][r] + bv_;
          uint32_t pk = __builtin_amdgcn_cvt_pk_fp8_f32(val, val, 0, false);
          vT8[(size_t)col * NTOK + fperm(row0 + r)] = (u8)(pk & 0xFF);
        }
      } else {
        u8* dst = (which == 0) ? qb8 : kb8;
        const int icol = (col & ~63) | ilv64(col & 63);   // k-interleave
        #pragma unroll
        for (int r = 0; r < 4; r++) {
          const float val = acc[i][j][r] + bv_;
          uint32_t pk = __builtin_amdgcn_cvt_pk_fp8_f32(val, val, 0, false);
          dst[(size_t)(row0 + r) * DD + icol] = (u8)(pk & 0xFF);
        }
      }
    }
  }
}

// ---------------- out projection: 256 thr, 128x128 tiles, bf16 in / fp32+resid out ----------------
__launch_bounds__(256, 3)
__global__ void outproj_kernel(const u16* __restrict__ A, const u16* __restrict__ BT,
                               const float* __restrict__ bias, float* __restrict__ outp,
                               const float* __restrict__ resid) {
  __shared__ __align__(16) u16 As[128 * 32];
  __shared__ __align__(16) u16 Bs[128 * 32];
  const int m0 = blockIdx.x * 128, n0 = blockIdx.y * 128;
  const int tid = threadIdx.x;
  const int w = tid >> 6, lane = tid & 63, lm = lane & 15, quad = lane >> 4;
  const int wm = w & 1, wn = w >> 1;
  f32x4 acc[4][4] = {};
  const int soff = tid * 16;
  const int srow = soff >> 6;
  const int scol = soff & 63;
  const char* Ag = (const char*)A + ((size_t)(m0 + srow) * DD) * 2 + scol;
  const char* Bg = (const char*)BT + ((size_t)(n0 + srow) * DD) * 2 + scol;
  char* Al = (char*)As + w * 1024;
  char* Bl = (char*)Bs + w * 1024;
  const size_t rs = (size_t)64 * DD * 2;
  for (int kk = 0; kk < DD; kk += 32) {
    const char* ag = Ag + (size_t)kk * 2;
    const char* bg = Bg + (size_t)kk * 2;
    gload16(ag, Al);
    gload16(ag + rs, Al + 4096);
    gload16(bg, Bl);
    gload16(bg + rs, Bl + 4096);
    __syncthreads();
    bf16x8 af[4], bfr[4];
    #pragma unroll
    for (int i = 0; i < 4; i++) af[i] = *(const bf16x8*)&As[(wm * 64 + i * 16 + lm) * 32 + quad * 8];
    #pragma unroll
    for (int j = 0; j < 4; j++) bfr[j] = *(const bf16x8*)&Bs[(wn * 64 + j * 16 + lm) * 32 + quad * 8];
    #pragma unroll
    for (int i = 0; i < 4; i++)
      #pragma unroll
      for (int j = 0; j < 4; j++)
        acc[i][j] = __builtin_amdgcn_mfma_f32_16x16x32_bf16(af[i], bfr[j], acc[i][j], 0, 0, 0);
    __syncthreads();
  }
  #pragma unroll
  for (int i = 0; i < 4; i++) {
    const int row0 = m0 + wm * 64 + i * 16 + quad * 4;
    #pragma unroll
    for (int j = 0; j < 4; j++) {
      const int col = n0 + wn * 64 + j * 16 + lm;
      const float bv = bias[col];
      #pragma unroll
      for (int r = 0; r < 4; r++) {
        const size_t idx = (size_t)(row0 + r) * DD + col;
        outp[idx] = acc[i][j][r] + bv + resid[idx];
      }
    }
  }
}

// ---------------- fp8 PV GEMM: 256 thr, 128x128 tiles, BK=64, swizzled b128 LDS reads ----------------
// contraction dim (tokens) interleaved via fperm on both P8 and vT8
// MODE 3: bf16 out scaled by 1/lsum[row]; MODE 4: fp32 partial, K-range by blockIdx.z
template <int MODE>
__launch_bounds__(256, 3)
__global__ void gemm_fp8_kernel(const u8* __restrict__ A, const u8* __restrict__ BT,
                                int K, int lda, int ldb, void* __restrict__ outp,
                                const float* __restrict__ lsum) {
  __shared__ __align__(16) u8 As[128 * 64];
  __shared__ __align__(16) u8 Bs[128 * 64];
  const int m0 = blockIdx.x * 128, n0 = blockIdx.y * 128;
  const int tid = threadIdx.x;
  const int w = tid >> 6, lane = tid & 63, lm = lane & 15, quad = lane >> 4;
  const int wm = w & 1, wn = w >> 1;
  f32x4 acc[4][4] = {};
  const int srow = tid >> 2;                                    // 0..63
  const int scol = ((tid & 3) ^ ((srow >> 1) & 3)) * 16;        // swizzled global chunk
  const size_t kbase = (MODE == 4) ? (size_t)blockIdx.z * (size_t)K : 0;
  const u8* Ag = A + (size_t)(m0 + srow) * lda + kbase + scol;
  const u8* Bg = BT + (size_t)(n0 + srow) * ldb + kbase + scol;
  u8* Al = As + w * 1024;
  u8* Bl = Bs + w * 1024;
  const size_t ars = (size_t)64 * lda;
  const size_t brs = (size_t)64 * ldb;
  const int csel = ((quad ^ ((lm >> 1) & 3)) * 16);
  for (int kk = 0; kk < K; kk += 64) {
    const u8* ag = Ag + kk;
    const u8* bg = Bg + kk;
    gload16(ag, Al);
    gload16(ag + ars, Al + 4096);
    gload16(bg, Bl);
    gload16(bg + brs, Bl + 4096);
    __syncthreads();
    i64x2 afv[4], bfv[4];
    #pragma unroll
    for (int i = 0; i < 4; i++)
      afv[i] = *(const i64x2*)&As[(wm * 64 + i * 16 + lm) * 64 + csel];
    #pragma unroll
    for (int j = 0; j < 4; j++)
      bfv[j] = *(const i64x2*)&Bs[(wn * 64 + j * 16 + lm) * 64 + csel];
    #pragma unroll
    for (int i = 0; i < 4; i++)
      #pragma unroll
      for (int j = 0; j < 4; j++) {
        acc[i][j] = __builtin_amdgcn_mfma_f32_16x16x32_fp8_fp8(afv[i].x, bfv[j].x, acc[i][j], 0, 0, 0);
        acc[i][j] = __builtin_amdgcn_mfma_f32_16x16x32_fp8_fp8(afv[i].y, bfv[j].y, acc[i][j], 0, 0, 0);
      }
    __syncthreads();
  }
  #pragma unroll
  for (int i = 0; i < 4; i++) {
    const int row0 = m0 + wm * 64 + i * 16 + quad * 4;
    float li[4];
    if (MODE == 3) {
      #pragma unroll
      for (int r = 0; r < 4; r++) li[r] = 1.0f / lsum[row0 + r];
    }
    #pragma unroll
    for (int j = 0; j < 4; j++) {
      const int col = n0 + wn * 64 + j * 16 + lm;
      if (MODE == 3) {
        #pragma unroll
        for (int r = 0; r < 4; r++)
          ((u16*)outp)[(size_t)(row0 + r) * DD + col] = f2bf(acc[i][j][r] * li[r]);
      } else {
        float* po = (float*)outp + (size_t)blockIdx.z * NTOK * DD;
        #pragma unroll
        for (int r = 0; r < 4; r++)
          po[(size_t)(row0 + r) * DD + col] = acc[i][j][r];
      }
    }
  }
}

// ---------------- split-K PV reduce (4 parts): attnb = (sum parts) / lsum ----------------
__global__ void pv_reduce_kernel(const float* __restrict__ part, const float* __restrict__ lsum,
                                 u16* __restrict__ attnb) {
  const int idx = blockIdx.x * 256 + threadIdx.x;
  const int row = idx >> 7;
  const int c4 = (idx & 127) << 2;
  const float* p = part + (size_t)row * DD + c4;
  const size_t stride = (size_t)NTOK * DD;
  float4 a = *(const float4*)(p);
  float4 b = *(const float4*)(p + stride);
  float4 c = *(const float4*)(p + 2 * stride);
  float4 d = *(const float4*)(p + 3 * stride);
  const float inv = 1.0f / lsum[row];
  ushort4 o;
  o.x = f2bf((a.x + b.x + c.x + d.x) * inv);
  o.y = f2bf((a.y + b.y + c.y + d.y) * inv);
  o.z = f2bf((a.z + b.z + c.z + d.z) * inv);
  o.w = f2bf((a.w + b.w + c.w + d.w) * inv);
  *(ushort4*)(attnb + (size_t)row * DD + c4) = o;
}

// ---------------- scores: fp8 QK^T, 128 q-rows x 512-key chunk, 1024 thr, BK=64 ----------------
// q/k fp8 k-interleaved; phase A applies SCLL inside exp2; fp8 P store (fperm layout)
__launch_bounds__(1024, 4)
__global__ void scores_kernel(const u8* __restrict__ qb8, const u8* __restrict__ kb8,
                              u8* __restrict__ P8, float* __restrict__ lsum) {
  __shared__ __align__(16) u8 As[128 * 64];   // 8 KB
  __shared__ __align__(16) u8 Bs[512 * 64];   // 32 KB
  __shared__ float hS[8][128], hP[8][128], hZ[128];
  const int m0 = blockIdx.x * 128;
  const int c = blockIdx.y;
  const int tid = threadIdx.x;
  const int w = tid >> 6, lane = tid & 63, lm = lane & 15, quad = lane >> 4;
  const int mt = w & 1, wsl = w >> 1;
  f32x4 s[4][4] = {};
  const int srA = tid >> 2;                                   // A: 0..127 ; B: 0..255
  const int scS = ((tid & 3) ^ ((srA >> 1) & 3)) * 16;        // staging swizzle
  const u8* Qg = qb8 + (size_t)(m0 + srA) * DD + scS;
  const u8* Kg = kb8 + (size_t)(c * CHK + srA) * DD + scS;
  u8* Al = As + w * 1024;
  u8* Bl = Bs + w * 1024;
  const int csel = ((quad ^ ((lm >> 1) & 3)) * 16);
  for (int kk = 0; kk < DD; kk += 64) {
    if (tid < 512) gload16(Qg + kk, Al);
    gload16(Kg + kk, Bl);
    gload16(Kg + kk + (size_t)256 * DD, Bl + 16384);
    __syncthreads();
    i64x2 afv[4], bfv[4];
    #pragma unroll
    for (int i = 0; i < 4; i++)
      afv[i] = *(const i64x2*)&As[(mt * 64 + i * 16 + lm) * 64 + csel];
    #pragma unroll
    for (int j = 0; j < 4; j++)
      bfv[j] = *(const i64x2*)&Bs[(wsl * 64 + j * 16 + lm) * 64 + csel];
    #pragma unroll
    for (int i = 0; i < 4; i++)
      #pragma unroll
      for (int j = 0; j < 4; j++) {
        s[i][j] = __builtin_amdgcn_mfma_f32_16x16x32_fp8_fp8(afv[i].x, bfv[j].x, s[i][j], 0, 0, 0);
        s[i][j] = __builtin_amdgcn_mfma_f32_16x16x32_fp8_fp8(afv[i].y, bfv[j].y, s[i][j], 0, 0, 0);
      }
    __syncthreads();
  }
  // ---- phase A: e = exp2(s_raw * SCL*LOG2E); per-wave (64-col) partial row sums (DPP) ----
  #pragma unroll
  for (int i = 0; i < 4; i++) {
    #pragma unroll
    for (int reg = 0; reg < 4; reg++) {
      float z = 0.f;
      #pragma unroll
      for (int j = 0; j < 4; j++) {
        float e = exp2f(s[i][j][reg] * SCLL);
        s[i][j][reg] = e;
        z += e;
      }
      z = rowsum16(z);
      if (lm == 0) hS[wsl][mt * 64 + i * 16 + quad * 4 + reg] = z;
    }
  }
  __syncthreads();
  // ---- phase B: row totals -> hZ = LOG2E / Z ----
  if (tid < 128) {
    float t = 0.f;
    #pragma unroll
    for (int w2 = 0; w2 < 8; w2++) t += hS[w2][tid];
    hZ[tid] = LOG2E / t;
  }
  __syncthreads();
  // ---- phase C: p = exp2(e * LOG2E/Z); fp8 packed store in fperm layout; partial l ----
  const int newc = ((lm >> 1) & 3) * 2 + (lm >> 3);
  const int pbyte = wsl * 64 + newc * 8 + (lm & 1) * 4;
  #pragma unroll
  for (int i = 0; i < 4; i++) {
    #pragma unroll
    for (int reg = 0; reg < 4; reg++) {
      const int rl = mt * 64 + i * 16 + quad * 4 + reg;
      const float iz = hZ[rl];
      const float p0 = exp2f(s[i][0][reg] * iz);
      const float p1 = exp2f(s[i][1][reg] * iz);
      const float p2 = exp2f(s[i][2][reg] * iz);
      const float p3 = exp2f(s[i][3][reg] * iz);
      float zp = (p0 + p1) + (p2 + p3);
      zp = rowsum16(zp);
      if (lm == 0) hP[wsl][rl] = zp;
      uint32_t o = __builtin_amdgcn_cvt_pk_fp8_f32(p0, p1, 0, false);
      o = __builtin_amdgcn_cvt_pk_fp8_f32(p2, p3, o, true);
      *(uint32_t*)(P8 + (size_t)(m0 + rl) * NTOK + c * CHK + pbyte) = o;
    }
  }
  __syncthreads();
  if (tid < 128) {
    float t = 0.f;
    #pragma unroll
    for (int w2 = 0; w2 < 8; w2++) t += hP[w2][tid];
    atomicAdd(&lsum[m0 + tid], t);
  }
}

// ---------------- cls row (exact fp32) ----------------
__global__ void cls_u_kernel(const float* __restrict__ Wk, const float* __restrict__ bk,
                             const float* __restrict__ q0g, float* __restrict__ uc) {
  __shared__ float q0[512];
  const int tid = threadIdx.x;
  q0[tid] = q0g[tid];
  q0[tid + 256] = q0g[tid + 256];
  __syncthreads();
  if (blockIdx.x < 8) {
    const int c = blockIdx.x * 64 + (tid >> 2), ii = tid & 3;
    float acc = 0.f;
    #pragma unroll 8
    for (int j = ii; j < 512; j += 4) acc += Wk[(size_t)c * 512 + j] * q0[j];
    acc += __shfl_xor(acc, 1, 64);
    acc += __shfl_xor(acc, 2, 64);
    if (ii == 0) uc[c] = acc;
  } else if (tid < 64) {
    float acc = 0.f;
    #pragma unroll 8
    for (int j = tid; j < 512; j += 64) acc += bk[j] * q0[j];
    #pragma unroll
    for (int off = 1; off < 64; off <<= 1) acc += __shfl_xor(acc, off, 64);
    if (tid == 0) uc[512] = acc;
  }
}

__global__ void cls_scores_kernel(const float* __restrict__ x, const float* __restrict__ uc,
                                  float* __restrict__ s0) {
  __shared__ float u[512];
  __shared__ float c0s;
  int tid = threadIdx.x;  // 256
  for (int i = tid; i < 512; i += 256) u[i] = uc[i];
  if (tid == 0) c0s = uc[512];
  __syncthreads();
  int rowg = blockIdx.x * 32 + (tid >> 3);
  int ii = tid & 7;
  const float* xr = x + rowg * 512;
  float acc = 0.f;
  for (int i = ii; i < 512; i += 8) acc += xr[i] * u[i];
  acc += __shfl_xor(acc, 1, 64);
  acc += __shfl_xor(acc, 2, 64);
  acc += __shfl_xor(acc, 4, 64);
  if (ii == 0) s0[rowg] = (acc + c0s) * SCL;
}

__global__ void cls_softmax_kernel(const float* __restrict__ s0, float* __restrict__ out) {
  int tid = threadIdx.x;  // 1024 = 16 waves, wave w = chunk w
  int w = tid >> 6, lane = tid & 63;
  const float* sc = s0 + w * 512;
  float v[8];
  float m = -1e30f;
  #pragma unroll
  for (int j = 0; j < 8; j++) { v[j] = sc[lane * 8 + j]; m = fmaxf(m, v[j]); }
  for (int off = 1; off < 64; off <<= 1) m = fmaxf(m, __shfl_xor(m, off, 64));
  float z = 0.f;
  #pragma unroll
  for (int j = 0; j < 8; j++) { v[j] = expf(v[j] - m); z += v[j]; }
  for (int off = 1; off < 64; off <<= 1) z += __shfl_xor(z, off, 64);
  float invz = 1.f / z;
  float l = 0.f;
  #pragma unroll
  for (int j = 0; j < 8; j++) { v[j] = expf(v[j] * invz); l += v[j]; }
  for (int off = 1; off < 64; off <<= 1) l += __shfl_xor(l, off, 64);
  __shared__ float lw[16];
  if (lane == 0) lw[w] = l;
  __syncthreads();
  float L = 0.f;
  for (int i = 0; i < 16; i++) L += lw[i];
  float invL = 1.f / L;
  #pragma unroll
  for (int j = 0; j < 8; j++) out[w * 512 + lane * 8 + j] = v[j] * invL;
}

extern "C" void kernel_launch(void* const* d_in, const int* in_sizes, int n_in,
                              void* d_out, int out_size, void* d_ws, size_t ws_size,
                              hipStream_t stream) {
  const float* x  = (const float*)d_in[0];
  const float* Wq = (const float*)d_in[1];
  const float* bq = (const float*)d_in[2];
  const float* Wk = (const float*)d_in[3];
  const float* bk = (const float*)d_in[4];
  const float* Wv = (const float*)d_in[5];
  const float* bv = (const float*)d_in[6];
  const float* Wo = (const float*)d_in[7];
  const float* bo = (const float*)d_in[8];
  float* out = (float*)d_out;

  char* ws = (char*)d_ws;
  u16* xb    = (u16*)(ws);                  // 8 MB
  u16* Wall  = (u16*)(ws + 8388608);        // 1.5 MB
  u16* WoT   = (u16*)(ws + 9961472);        // 512 KB
  u8*  qb8   = (u8*)(ws + 10485760);        // 4 MB fp8 (k-interleaved)
  u8*  kb8   = (u8*)(ws + 14680064);        // 4 MB fp8 (k-interleaved)
  u8*  vT8   = (u8*)(ws + 18874368);        // 4 MB fp8 (fperm tokens)
  u16* attnb = (u16*)(ws + 23068672);       // 8 MB
  float* q0g = (float*)(ws + 31457280);     // 512 f
  float* uc  = (float*)(ws + 31461376);     // 513 f
  float* s0  = (float*)(ws + 31465472);     // 8192 f
  float* lsum= (float*)(ws + 31498240);     // 8192 f
  u8*  P8    = (u8*)(ws + 31531008);        // 64 MB fp8 (fperm token cols)
  float* part= (float*)(ws + 98639872);     // 4 x 16 MB
  const size_t need_full = 98639872ULL + (size_t)KSPLIT * NTOK * DD * 4ULL;

  prep_kernel<<<5122, 256, 0, stream>>>(x, Wq, Wk, Wv, Wo, bq, xb, Wall, WoT, lsum, q0g);

  qkv_kernel<<<dim3(NTOK / 128, 12), 256, 0, stream>>>(xb, Wall, bq, bk, bv, qb8, kb8, vT8);

  scores_kernel<<<dim3(NTOK / 128, NCH), 1024, 0, stream>>>(qb8, kb8, P8, lsum);

  if (ws_size >= need_full) {
    gemm_fp8_kernel<4><<<dim3(NTOK / 128, DD / 128, KSPLIT), 256, 0, stream>>>(
        P8, vT8, KLEN, NTOK, NTOK, part, nullptr);
    pv_reduce_kernel<<<NTOK * DD / 4 / 256, 256, 0, stream>>>(part, lsum, attnb);
  } else {
    gemm_fp8_kernel<3><<<dim3(NTOK / 128, DD / 128), 256, 0, stream>>>(
        P8, vT8, NTOK, NTOK, NTOK, attnb, lsum);
  }

  outproj_kernel<<<dim3(NTOK / 128, DD / 128), 256, 0, stream>>>(attnb, WoT, bo, out, x);

  cls_u_kernel<<<9, 256, 0, stream>>>(Wk, bk, q0g, uc);
  cls_scores_kernel<<<NTOK / 32, 256, 0, stream>>>(x, uc, s0);
  cls_softmax_kernel<<<1, 1024, 0, stream>>>(s0, out + (size_t)NTOK * DD);
}